// Round 9
// baseline (325.771 us; speedup 1.0000x reference)
//
#include <hip/hip_runtime.h>
#include <hip/hip_bf16.h>

// SimpleAttention fused block on MI355X (gfx950), bf16 MFMA pipeline.
// B=2, S=2048, D_MODEL=2048, H=16, DK=128.
//
// R9: remove manual lgkmcnt + mid-tile sched_barrier from GEMM inner loops
//     (rule #18/m141: order-pinning defeated the compiler's fine-grained
//     waitcnt scheduling). All 14 frags read up-front; compiler interleaves
//     ds_read completion with MFMA issue. Structural sync unchanged:
//     counted vmcnt staging FIFO + one barrier per K-tile.
//
// ws layout (bytes):          size
//  xb      [4096,2048] bf16    16M @ 0
//  wqkvb   [6144,2048] bf16    24M @ 16M
//  wob     [2048,2048] bf16     8M @ 40M
//  Qb  [B,H,S,128] bf16        16M @ 48M
//  Kb  [B,H,S,128] bf16        16M @ 64M
//  Vt  [B,H,128,S] bf16        16M @ 80M
//  Ao  [B,S,2048]  bf16        16M @ 96M
//  ctab [2048,64] f32         512K @ 112M
//  stab [2048,64] f32         512K @ 113M

typedef __bf16 bf16;
typedef __bf16 bf16x4 __attribute__((ext_vector_type(4)));
typedef __bf16 bf16x8 __attribute__((ext_vector_type(8)));
typedef float f32x4 __attribute__((ext_vector_type(4)));
typedef float f32x16 __attribute__((ext_vector_type(16)));
typedef int i32x4 __attribute__((ext_vector_type(4)));

#define DEV __device__ __forceinline__

DEV void gll16(const void* g, void* lds_base_wave_uniform) {
  __builtin_amdgcn_global_load_lds((const __attribute__((address_space(1))) void*)g,
                                   (__attribute__((address_space(3))) void*)lds_base_wave_uniform,
                                   16, 0, 0);
}

DEV f32x4 mfma16(bf16x8 a, bf16x8 b, f32x4 c) {
  return __builtin_amdgcn_mfma_f32_16x16x32_bf16(a, b, c, 0, 0, 0);
}
DEV f32x16 mfma32(bf16x8 a, bf16x8 b, f32x16 c) {
  return __builtin_amdgcn_mfma_f32_32x32x16_bf16(a, b, c, 0, 0, 0);
}

DEV int pack2(float x, float y) {
  union { bf16 h[2]; int i; } u;
  u.h[0] = (bf16)x; u.h[1] = (bf16)y;
  return u.i;
}

// ---------------- f32 -> bf16 convert ----------------
__global__ __launch_bounds__(256) void cvt_f32_bf16(const float* __restrict__ in,
                                                    bf16* __restrict__ out, int n) {
  int i = (blockIdx.x * 256 + threadIdx.x) << 3;
  if (i >= n) return;
  float4 a = *(const float4*)(in + i);
  float4 b = *(const float4*)(in + i + 4);
  bf16x8 o;
  o[0] = (bf16)a.x; o[1] = (bf16)a.y; o[2] = (bf16)a.z; o[3] = (bf16)a.w;
  o[4] = (bf16)b.x; o[5] = (bf16)b.y; o[6] = (bf16)b.z; o[7] = (bf16)b.w;
  *(bf16x8*)(out + i) = o;
}

// ---------------- rope tables ----------------
// freq[j] = 10000^(-j/63)  (linspace(0,1,64) inclusive!)
__global__ __launch_bounds__(256) void rope_table(float* __restrict__ ctab,
                                                  float* __restrict__ stab) {
  int id = blockIdx.x * 256 + threadIdx.x;  // 2048*64
  int s = id >> 6, j = id & 63;
  float freq = powf(10000.0f, -(float)j / 63.0f);
  float th = (float)s * freq;
  ctab[id] = cosf(th);
  stab[id] = sinf(th);
}

// ---------------- in-place rope on Qb (with scale) and Kb, bf16x8 ----------------
__global__ __launch_bounds__(256) void rope_apply(bf16* __restrict__ Qb, bf16* __restrict__ Kb,
                                                  const float* __restrict__ ctab,
                                                  const float* __restrict__ stab) {
  const float QSCALE = 0.08838834764831845f * 1.4426950408889634f;
  int id = blockIdx.x * 256 + threadIdx.x;  // 2 * 32*2048*8
  const int half = 32 * 2048 * 8;
  bf16* P = (id < half) ? Qb : Kb;
  const float scale = (id < half) ? QSCALE : 1.0f;
  int t = (id < half) ? id : id - half;
  const int d0 = (t & 7) << 3;        // 8 rotary pairs per thread
  const int s = (t >> 3) & 2047;
  const int bh = t >> 14;
  bf16* p = P + (((size_t)bh * 2048 + s) << 7);
  bf16x8 x1 = *(bf16x8*)(p + d0);
  bf16x8 x2 = *(bf16x8*)(p + d0 + 64);
  float4 ca = *(const float4*)(ctab + (s << 6) + d0);
  float4 cb = *(const float4*)(ctab + (s << 6) + d0 + 4);
  float4 sa = *(const float4*)(stab + (s << 6) + d0);
  float4 sb = *(const float4*)(stab + (s << 6) + d0 + 4);
  const float c[8] = {ca.x, ca.y, ca.z, ca.w, cb.x, cb.y, cb.z, cb.w};
  const float sn[8] = {sa.x, sa.y, sa.z, sa.w, sb.x, sb.y, sb.z, sb.w};
  bf16x8 y1, y2;
#pragma unroll
  for (int j = 0; j < 8; ++j) {
    const float a = (float)x1[j], b = (float)x2[j];
    y1[j] = (bf16)((a * c[j] - b * sn[j]) * scale);
    y2[j] = (bf16)((a * sn[j] + b * c[j]) * scale);
  }
  *(bf16x8*)(p + d0) = y1;
  *(bf16x8*)(p + d0 + 64) = y2;
}

// ---------------- 256x384 BK=32 triple-buffer GEMM (QKV): C = A * Bt^T -------
// Grid 16x16 = 256 blocks (one clean round). Waves 2M x 4N: per-wave C =
// 128x96 = acc[8][6] (AGPR). Per K-tile: {14 ds_read (all frags) | STAGE t+2
// (5 gll16) | 48 MFMA (compiler-scheduled waits) | vmcnt(5) | barrier}.
__global__ __launch_bounds__(512, 2) void gemm384(const bf16* __restrict__ A,
                                                  const bf16* __restrict__ Bt,
                                                  bf16* __restrict__ q_out,
                                                  bf16* __restrict__ k_out,
                                                  bf16* __restrict__ v_out) {
  constexpr int K = 2048, NKT = 64;
  constexpr int BUFB = 40960;  // A 16384 + B 24576
  __shared__ char lds[3 * BUFB];  // 120 KiB
  const int id = blockIdx.x;
  const int swz = (id & 7) * 32 + (id >> 3);  // XCD swizzle (256 blocks)
  const int bx = swz & 15, by = swz >> 4;
  const int m0 = by << 8;      // 256-row M tile
  const int n0 = bx * 384;     // 384-col N tile
  const int tid = threadIdx.x, w = tid >> 6, l = tid & 63;
  const int wm = w >> 2, wn = w & 3;
  // staging decode (verified 0 bank conflicts)
  const int lsl = (l & 7) ^ ((l >> 3) & 7);
  const int srow = ((l >> 3) << 1) + (lsl >> 2);
  const int scol = (lsl & 3) << 3;

  auto STAGE = [&](int t, char* base) {
    const int k0 = t << 5;
#pragma unroll
    for (int c = 0; c < 2; ++c) {  // A: 256 rows = 2 issues
      const int row = (c << 7) + (w << 4) + srow;
      gll16(A + (size_t)(m0 + row) * K + k0 + scol, base + (c << 13) + (w << 10));
    }
#pragma unroll
    for (int c = 0; c < 3; ++c) {  // B: 384 rows = 3 issues
      const int row = (c << 7) + (w << 4) + srow;
      gll16(Bt + (size_t)(n0 + row) * K + k0 + scol, base + 16384 + (c << 13) + (w << 10));
    }
  };

  f32x4 acc[8][6] = {};

  STAGE(0, (char*)lds);
  STAGE(1, (char*)lds + BUFB);
  asm volatile("s_waitcnt vmcnt(5)" ::: "memory");
  __builtin_amdgcn_s_barrier();

#pragma unroll 1
  for (int t = 0, bi = 0, bj = 2; t < NKT; ++t) {
    char* rbase = (char*)lds + bi * BUFB;
    bf16x8 bfr[6], af[8];
#pragma unroll
    for (int j = 0; j < 6; ++j) {
      const int row = wn * 96 + (j << 4) + (l & 15);
      const int sr = row >> 1;
      bfr[j] = *(const bf16x8*)(rbase + 16384 + sr * 128 +
                                (((((row & 1) << 2) | (l >> 4)) ^ (sr & 7)) << 4));
    }
#pragma unroll
    for (int i = 0; i < 8; ++i) {
      const int row = (wm << 7) + (i << 4) + (l & 15);
      const int sr = row >> 1;
      af[i] = *(const bf16x8*)(rbase + sr * 128 +
                               (((((row & 1) << 2) | (l >> 4)) ^ (sr & 7)) << 4));
    }
    if (t + 2 < NKT) STAGE(t + 2, (char*)lds + bj * BUFB);
    __builtin_amdgcn_s_setprio(1);
#pragma unroll
    for (int i = 0; i < 8; ++i)
#pragma unroll
      for (int j = 0; j < 6; ++j)
        acc[i][j] = mfma16(af[i], bfr[j], acc[i][j]);
    __builtin_amdgcn_s_setprio(0);
    if (t + 2 < NKT) {
      asm volatile("s_waitcnt vmcnt(5)" ::: "memory");
    } else if (t + 2 == NKT) {
      asm volatile("s_waitcnt vmcnt(0)" ::: "memory");
    }
    __builtin_amdgcn_sched_barrier(0);
    __builtin_amdgcn_s_barrier();
    bi = (bi == 2) ? 0 : bi + 1;
    bj = (bj == 2) ? 0 : bj + 1;
  }

  // epilogue: frag (i,j): m = m0+wm*128+i*16+(l>>4)*4+r, nl = n0+wn*96+j*16+(l&15)
#pragma unroll
  for (int i = 0; i < 8; ++i)
#pragma unroll
    for (int j = 0; j < 6; ++j) {
      const int nl = n0 + wn * 96 + (j << 4) + (l & 15);
      const int which = nl >> 11;
      const int h = (nl >> 7) & 15, d = nl & 127;
      if (which < 2) {
        bf16* dst = which ? k_out : q_out;
#pragma unroll
        for (int r = 0; r < 4; ++r) {
          const int m = m0 + (wm << 7) + (i << 4) + ((l >> 4) << 2) + r;
          const int b_ = m >> 11, s = m & 2047;
          dst[(((size_t)((b_ << 4) | h)) * 2048 + s) * 128 + d] = (bf16)acc[i][j][r];
        }
      } else {
        const int sb = m0 + (wm << 7) + (i << 4) + ((l >> 4) << 2);
        const int b_ = sb >> 11, s = sb & 2047;
        bf16x4 vv;
#pragma unroll
        for (int r = 0; r < 4; ++r) vv[r] = (bf16)acc[i][j][r];
        *(bf16x4*)(v_out + ((size_t)((b_ << 4) | h) << 18) + ((size_t)d << 11) + s) = vv;
      }
    }
}

// ---------------- 128x256 BK=32 triple-buffer GEMM (out-proj), f32 out -------
template <int NTN>  // NTN = N/256
__global__ __launch_bounds__(512, 4) void gemm_p(const bf16* __restrict__ A,
                                                 const bf16* __restrict__ Bt,
                                                 float* __restrict__ f_out) {
  constexpr int K = 2048, NKT = K / 32;
  constexpr int BUFB = 24576;
  __shared__ bf16 lds[3 * 12288];
  const int nwg = NTN * 32;
  const int id = blockIdx.x;
  const int swz = (id & 7) * (nwg >> 3) + (id >> 3);
  const int bx = swz % NTN, by = swz / NTN;
  const int m0 = by << 7, n0 = bx << 8;
  const int tid = threadIdx.x, w = tid >> 6, l = tid & 63;
  const int wm = w >> 2, wn = w & 3;
  const int lsl = (l & 7) ^ ((l >> 3) & 7);
  const int srow = ((l >> 3) << 1) + (lsl >> 2);
  const int scol = (lsl & 3) << 3;

  auto STAGE = [&](int t, char* base) {
    const int k0 = t << 5;
    {
      const int row = (w << 4) + srow;
      gll16(A + (size_t)(m0 + row) * K + k0 + scol, base + (w << 10));
    }
#pragma unroll
    for (int s2 = 0; s2 < 2; ++s2) {
      const int row = (s2 << 7) + (w << 4) + srow;
      gll16(Bt + (size_t)(n0 + row) * K + k0 + scol, base + 8192 + (s2 << 13) + (w << 10));
    }
  };

  f32x4 acc[4][4] = {};

  STAGE(0, (char*)lds);
  STAGE(1, (char*)lds + BUFB);
  asm volatile("s_waitcnt vmcnt(3)" ::: "memory");
  __builtin_amdgcn_s_barrier();

#pragma unroll 1
  for (int t = 0, bi = 0, bj = 2; t < NKT; ++t) {
    char* rbase = (char*)lds + bi * BUFB;
    bf16x8 af[4], bfr[4];
#pragma unroll
    for (int i = 0; i < 4; ++i) {
      const int row = (wm << 6) + (i << 4) + (l & 15);
      const int sr = row >> 1;
      af[i] = *(const bf16x8*)(rbase + sr * 128 +
                               (((((row & 1) << 2) | (l >> 4)) ^ (sr & 7)) << 4));
    }
#pragma unroll
    for (int j = 0; j < 4; ++j) {
      const int row = (wn << 6) + (j << 4) + (l & 15);
      const int sr = row >> 1;
      bfr[j] = *(const bf16x8*)(rbase + 8192 + sr * 128 +
                                (((((row & 1) << 2) | (l >> 4)) ^ (sr & 7)) << 4));
    }
    if (t + 2 < NKT) STAGE(t + 2, (char*)lds + bj * BUFB);
    __builtin_amdgcn_s_setprio(1);
#pragma unroll
    for (int i = 0; i < 4; ++i)
#pragma unroll
      for (int j = 0; j < 4; ++j)
        acc[i][j] = mfma16(af[i], bfr[j], acc[i][j]);
    __builtin_amdgcn_s_setprio(0);
    if (t + 2 < NKT) {
      asm volatile("s_waitcnt vmcnt(3)" ::: "memory");
    } else if (t + 2 == NKT) {
      asm volatile("s_waitcnt vmcnt(0)" ::: "memory");
    }
    __builtin_amdgcn_sched_barrier(0);
    __builtin_amdgcn_s_barrier();
    bi = (bi == 2) ? 0 : bi + 1;
    bj = (bj == 2) ? 0 : bj + 1;
  }

#pragma unroll
  for (int i = 0; i < 4; ++i)
#pragma unroll
    for (int j = 0; j < 4; ++j)
#pragma unroll
      for (int r = 0; r < 4; ++r) {
        const int m = m0 + (wm << 6) + (i << 4) + ((l >> 4) << 2) + r;
        const int n = n0 + (wn << 6) + (j << 4) + (l & 15);
        f_out[(size_t)m * 2048 + n] = acc[i][j][r];
      }
}

// ---------------- causal flash attention, swapped-operand 32x32 ----------------
// grid 512 = B*H*16 q-tiles; 4 waves x QBLK=32 rows = QB 128; KVBLK=64.
// Double-buffered K/V: next tile's 8 gll16 issued BEFORE compute; setprio.
__global__ __launch_bounds__(256, 2) void attn_kernel(const bf16* __restrict__ Qb,
                                                      const bf16* __restrict__ Kb,
                                                      const bf16* __restrict__ Vt,
                                                      bf16* __restrict__ Ao) {
  constexpr int S = 2048;
  __shared__ bf16 Ks[2][64 * 128];
  __shared__ bf16 Vs[2][128 * 64];
  const int idx = blockIdx.x;
  const int bh = idx >> 4;
  int qt = idx & 15;
  if (idx & 256) qt = 15 - qt;
  const int q0 = qt << 7;
  const int tid = threadIdx.x, w = tid >> 6, l = tid & 63;
  const int hi = l >> 5;
  const bf16* Qp = Qb + ((size_t)bh << 18);
  const bf16* Kp = Kb + ((size_t)bh << 18);
  const bf16* Vp = Vt + ((size_t)bh << 18);

  auto STAGE_KV = [&](int kv0, int bufi) {
    char* Kbase = (char*)Ks + (bufi << 14);
    char* Vbase = (char*)Vs + (bufi << 14);
#pragma unroll
    for (int i = 0; i < 4; ++i) {
      const int rk = (w << 4) + (i << 2) + (l >> 4);
      gll16(Kp + ((size_t)(kv0 + rk) << 7) + (((l & 15) ^ (rk & 7)) << 3),
            Kbase + (w << 12) + (i << 10));
      const int rv = (w << 5) + (i << 3) + (l >> 3);
      gll16(Vp + (size_t)rv * S + kv0 + (((l & 7) ^ (rv & 7)) << 3),
            Vbase + (w << 12) + (i << 10));
    }
  };

  bf16x8 qf[8];
#pragma unroll
  for (int kt = 0; kt < 8; ++kt)
    qf[kt] = *(const bf16x8*)(Qp + ((size_t)(q0 + (w << 5) + (l & 31)) << 7) + (kt << 4) + (hi << 3));

  f32x16 o[4] = {};
  float mrun = -3e38f, lrun = 0.f;

  const int qminw = q0 + (w << 5);
  const int qmaxw = qminw + 31;
  const int kv_end = q0 + 128;

  STAGE_KV(0, 0);
  __syncthreads();

  int bufi = 0;
#pragma unroll 1
  for (int kv0 = 0; kv0 < kv_end; kv0 += 64, bufi ^= 1) {
    if (kv0 + 64 < kv_end) STAGE_KV(kv0 + 64, bufi ^ 1);
    if (kv0 <= qmaxw) {
      const char* Kbase = (const char*)Ks + (bufi << 14);
      const char* Vbase = (const char*)Vs + (bufi << 14);
      f32x16 sc0 = {}, sc1 = {};
      __builtin_amdgcn_s_setprio(1);
#pragma unroll
      for (int kt = 0; kt < 8; ++kt) {
        const int rk0 = l & 31;
        const int coff = ((kt << 5) + (hi << 4));
        bf16x8 k0 = *(const bf16x8*)(Kbase + (rk0 << 8) + (coff ^ ((rk0 & 7) << 4)));
        bf16x8 k1 = *(const bf16x8*)(Kbase + ((rk0 + 32) << 8) + (coff ^ ((rk0 & 7) << 4)));
        sc0 = mfma32(k0, qf[kt], sc0);
        sc1 = mfma32(k1, qf[kt], sc1);
      }
      __builtin_amdgcn_s_setprio(0);
      if (kv0 + 63 > qminw) {
        const int qg = qminw + (l & 31);
#pragma unroll
        for (int r = 0; r < 16; ++r) {
          const int kvr = kv0 + (r & 3) + ((r >> 2) << 3) + (hi << 2);
          if (kvr > qg) sc0[r] = -3e38f;
          if (kvr + 32 > qg) sc1[r] = -3e38f;
        }
      }
      float mx = -3e38f;
#pragma unroll
      for (int r = 0; r < 16; ++r) mx = fmaxf(mx, fmaxf(sc0[r], sc1[r]));
      mx = fmaxf(mx, __shfl_xor(mx, 32));
      const float mnew = fmaxf(mrun, mx);
      if (!__all(mx <= mrun)) {
        const float alpha = exp2f(mrun - mnew);
        lrun *= alpha;
#pragma unroll
        for (int dt = 0; dt < 4; ++dt) o[dt] *= alpha;
      }
      mrun = mnew;
      float ps = 0.f;
#pragma unroll
      for (int r = 0; r < 16; ++r) {
        sc0[r] = exp2f(sc0[r] - mnew); ps += sc0[r];
        sc1[r] = exp2f(sc1[r] - mnew); ps += sc1[r];
      }
      ps += __shfl_xor(ps, 32);
      lrun += ps;
#pragma unroll
      for (int ks = 0; ks < 4; ++ks) {
        const f32x16& s = (ks & 2) ? sc1 : sc0;
        const int rb = (ks & 1) << 3;
        int pa_ = pack2(s[rb + 0], s[rb + 1]);
        int pb_ = pack2(s[rb + 2], s[rb + 3]);
        int pc_ = pack2(s[rb + 4], s[rb + 5]);
        int pd_ = pack2(s[rb + 6], s[rb + 7]);
        int sa = __shfl_xor(pa_, 32), sb = __shfl_xor(pb_, 32);
        int sc_ = __shfl_xor(pc_, 32), sd = __shfl_xor(pd_, 32);
        i32x4 pi;
        pi[0] = hi ? sc_ : pa_;
        pi[1] = hi ? sd : pb_;
        pi[2] = hi ? pc_ : sa;
        pi[3] = hi ? pd_ : sb;
        const bf16x8 pf = __builtin_bit_cast(bf16x8, pi);
        __builtin_amdgcn_s_setprio(1);
#pragma unroll
        for (int dt = 0; dt < 4; ++dt) {
          const int rd = (dt << 5) + (l & 31);
          const bf16x8 vf = *(const bf16x8*)(Vbase + (rd << 7) +
                                             (((ks << 5) + (hi << 4)) ^ ((rd & 7) << 4)));
          o[dt] = mfma32(vf, pf, o[dt]);
        }
        __builtin_amdgcn_s_setprio(0);
      }
    }
    __syncthreads();
  }
  const float rinv = 1.0f / lrun;
  const int b = bh >> 4, h = bh & 15;
  const int qg = q0 + (w << 5) + (l & 31);
  bf16* Arow = Ao + (((size_t)(b * S + qg)) << 11) + (h << 7);
#pragma unroll
  for (int dt = 0; dt < 4; ++dt)
#pragma unroll
    for (int g = 0; g < 4; ++g) {
      bf16x4 ov;
#pragma unroll
      for (int r = 0; r < 4; ++r) ov[r] = (bf16)(o[dt][(g << 2) + r] * rinv);
      *(bf16x4*)(Arow + (dt << 5) + (g << 3) + (hi << 2)) = ov;
    }
}

// ---------------- launch ----------------
extern "C" void kernel_launch(void* const* d_in, const int* in_sizes, int n_in,
                              void* d_out, int out_size, void* d_ws, size_t ws_size,
                              hipStream_t stream) {
  const float* x = (const float*)d_in[0];      // [2,2048,2048]
  const float* w_qkv = (const float*)d_in[1];  // [6144,2048]
  const float* w_o = (const float*)d_in[2];    // [2048,2048]
  float* out = (float*)d_out;                  // [2,2048,2048] f32
  char* ws = (char*)d_ws;

  bf16* xb    = (bf16*)(ws);
  bf16* wqkvb = (bf16*)(ws + (16ull << 20));
  bf16* wob   = (bf16*)(ws + (40ull << 20));
  bf16* Qb    = (bf16*)(ws + (48ull << 20));
  bf16* Kb    = (bf16*)(ws + (64ull << 20));
  bf16* Vt    = (bf16*)(ws + (80ull << 20));
  bf16* Ao    = (bf16*)(ws + (96ull << 20));
  float* ctab = (float*)(ws + (112ull << 20));
  float* stab = (float*)(ws + (113ull << 20));

  cvt_f32_bf16<<<4096, 256, 0, stream>>>(x, xb, 2 * 2048 * 2048);
  cvt_f32_bf16<<<6144, 256, 0, stream>>>(w_qkv, wqkvb, 6144 * 2048);
  cvt_f32_bf16<<<2048, 256, 0, stream>>>(w_o, wob, 2048 * 2048);
  rope_table<<<512, 256, 0, stream>>>(ctab, stab);
  gemm384<<<256, 512, 0, stream>>>(xb, wqkvb, Qb, Kb, Vt);
  rope_apply<<<4096, 256, 0, stream>>>(Qb, Kb, ctab, stab);
  attn_kernel<<<512, 256, 0, stream>>>(Qb, Kb, Vt, Ao);
  gemm_p<8><<<256, 512, 0, stream>>>(Ao, wob, out);
}

// Round 10
// 258.261 us; speedup vs baseline: 1.2614x; 1.2614x over previous
//
#include <hip/hip_runtime.h>
#include <hip/hip_bf16.h>

// SimpleAttention fused block on MI355X (gfx950), bf16 MFMA pipeline.
// B=2, S=2048, D_MODEL=2048, H=16, DK=128.
//
// R10: gemm384 reverted to R8 two-cluster form (R9's fused 14-frag read
//      spilled: WRITE_SIZE 56->172MB). Out-proj rebuilt as gemm_o:
//      128x128, 4 waves, BK=32, triple-buffer 48KiB, vmcnt(4) FIFO,
//      grid 512 => ~3 blocks/CU co-resident (R7-R9 ran it 1/CU, ~300 TF).
//
// ws layout (bytes):          size
//  xb      [4096,2048] bf16    16M @ 0
//  wqkvb   [6144,2048] bf16    24M @ 16M
//  wob     [2048,2048] bf16     8M @ 40M
//  Qb  [B,H,S,128] bf16        16M @ 48M
//  Kb  [B,H,S,128] bf16        16M @ 64M
//  Vt  [B,H,128,S] bf16        16M @ 80M
//  Ao  [B,S,2048]  bf16        16M @ 96M
//  ctab [2048,64] f32         512K @ 112M
//  stab [2048,64] f32         512K @ 113M

typedef __bf16 bf16;
typedef __bf16 bf16x4 __attribute__((ext_vector_type(4)));
typedef __bf16 bf16x8 __attribute__((ext_vector_type(8)));
typedef float f32x4 __attribute__((ext_vector_type(4)));
typedef float f32x16 __attribute__((ext_vector_type(16)));
typedef int i32x4 __attribute__((ext_vector_type(4)));

#define DEV __device__ __forceinline__

DEV void gll16(const void* g, void* lds_base_wave_uniform) {
  __builtin_amdgcn_global_load_lds((const __attribute__((address_space(1))) void*)g,
                                   (__attribute__((address_space(3))) void*)lds_base_wave_uniform,
                                   16, 0, 0);
}

DEV f32x4 mfma16(bf16x8 a, bf16x8 b, f32x4 c) {
  return __builtin_amdgcn_mfma_f32_16x16x32_bf16(a, b, c, 0, 0, 0);
}
DEV f32x16 mfma32(bf16x8 a, bf16x8 b, f32x16 c) {
  return __builtin_amdgcn_mfma_f32_32x32x16_bf16(a, b, c, 0, 0, 0);
}

DEV int pack2(float x, float y) {
  union { bf16 h[2]; int i; } u;
  u.h[0] = (bf16)x; u.h[1] = (bf16)y;
  return u.i;
}

// ---------------- f32 -> bf16 convert ----------------
__global__ __launch_bounds__(256) void cvt_f32_bf16(const float* __restrict__ in,
                                                    bf16* __restrict__ out, int n) {
  int i = (blockIdx.x * 256 + threadIdx.x) << 3;
  if (i >= n) return;
  float4 a = *(const float4*)(in + i);
  float4 b = *(const float4*)(in + i + 4);
  bf16x8 o;
  o[0] = (bf16)a.x; o[1] = (bf16)a.y; o[2] = (bf16)a.z; o[3] = (bf16)a.w;
  o[4] = (bf16)b.x; o[5] = (bf16)b.y; o[6] = (bf16)b.z; o[7] = (bf16)b.w;
  *(bf16x8*)(out + i) = o;
}

// ---------------- rope tables ----------------
// freq[j] = 10000^(-j/63)  (linspace(0,1,64) inclusive!)
__global__ __launch_bounds__(256) void rope_table(float* __restrict__ ctab,
                                                  float* __restrict__ stab) {
  int id = blockIdx.x * 256 + threadIdx.x;  // 2048*64
  int s = id >> 6, j = id & 63;
  float freq = powf(10000.0f, -(float)j / 63.0f);
  float th = (float)s * freq;
  ctab[id] = cosf(th);
  stab[id] = sinf(th);
}

// ---------------- in-place rope on Qb (with scale) and Kb, bf16x8 ----------------
__global__ __launch_bounds__(256) void rope_apply(bf16* __restrict__ Qb, bf16* __restrict__ Kb,
                                                  const float* __restrict__ ctab,
                                                  const float* __restrict__ stab) {
  const float QSCALE = 0.08838834764831845f * 1.4426950408889634f;
  int id = blockIdx.x * 256 + threadIdx.x;  // 2 * 32*2048*8
  const int half = 32 * 2048 * 8;
  bf16* P = (id < half) ? Qb : Kb;
  const float scale = (id < half) ? QSCALE : 1.0f;
  int t = (id < half) ? id : id - half;
  const int d0 = (t & 7) << 3;        // 8 rotary pairs per thread
  const int s = (t >> 3) & 2047;
  const int bh = t >> 14;
  bf16* p = P + (((size_t)bh * 2048 + s) << 7);
  bf16x8 x1 = *(bf16x8*)(p + d0);
  bf16x8 x2 = *(bf16x8*)(p + d0 + 64);
  float4 ca = *(const float4*)(ctab + (s << 6) + d0);
  float4 cb = *(const float4*)(ctab + (s << 6) + d0 + 4);
  float4 sa = *(const float4*)(stab + (s << 6) + d0);
  float4 sb = *(const float4*)(stab + (s << 6) + d0 + 4);
  const float c[8] = {ca.x, ca.y, ca.z, ca.w, cb.x, cb.y, cb.z, cb.w};
  const float sn[8] = {sa.x, sa.y, sa.z, sa.w, sb.x, sb.y, sb.z, sb.w};
  bf16x8 y1, y2;
#pragma unroll
  for (int j = 0; j < 8; ++j) {
    const float a = (float)x1[j], b = (float)x2[j];
    y1[j] = (bf16)((a * c[j] - b * sn[j]) * scale);
    y2[j] = (bf16)((a * sn[j] + b * c[j]) * scale);
  }
  *(bf16x8*)(p + d0) = y1;
  *(bf16x8*)(p + d0 + 64) = y2;
}

// ---------------- 256x384 BK=32 triple-buffer GEMM (QKV): C = A * Bt^T -------
// R8 structure (96us, MfmaUtil 46%): two 24-MFMA clusters with A-frag reload
// between them (keeps live frag set <= 40 regs; fusing spilled in R9).
__global__ __launch_bounds__(512, 2) void gemm384(const bf16* __restrict__ A,
                                                  const bf16* __restrict__ Bt,
                                                  bf16* __restrict__ q_out,
                                                  bf16* __restrict__ k_out,
                                                  bf16* __restrict__ v_out) {
  constexpr int K = 2048, NKT = 64;
  constexpr int BUFB = 40960;  // A 16384 + B 24576
  __shared__ char lds[3 * BUFB];  // 120 KiB
  const int id = blockIdx.x;
  const int swz = (id & 7) * 32 + (id >> 3);  // XCD swizzle (256 blocks)
  const int bx = swz & 15, by = swz >> 4;
  const int m0 = by << 8;      // 256-row M tile
  const int n0 = bx * 384;     // 384-col N tile
  const int tid = threadIdx.x, w = tid >> 6, l = tid & 63;
  const int wm = w >> 2, wn = w & 3;
  // staging decode (verified 0 bank conflicts)
  const int lsl = (l & 7) ^ ((l >> 3) & 7);
  const int srow = ((l >> 3) << 1) + (lsl >> 2);
  const int scol = (lsl & 3) << 3;

  auto STAGE = [&](int t, char* base) {
    const int k0 = t << 5;
#pragma unroll
    for (int c = 0; c < 2; ++c) {  // A: 256 rows = 2 issues
      const int row = (c << 7) + (w << 4) + srow;
      gll16(A + (size_t)(m0 + row) * K + k0 + scol, base + (c << 13) + (w << 10));
    }
#pragma unroll
    for (int c = 0; c < 3; ++c) {  // B: 384 rows = 3 issues
      const int row = (c << 7) + (w << 4) + srow;
      gll16(Bt + (size_t)(n0 + row) * K + k0 + scol, base + 16384 + (c << 13) + (w << 10));
    }
  };

  f32x4 acc[8][6] = {};

  STAGE(0, (char*)lds);
  STAGE(1, (char*)lds + BUFB);
  asm volatile("s_waitcnt vmcnt(5)" ::: "memory");
  __builtin_amdgcn_s_barrier();

#pragma unroll 1
  for (int t = 0, bi = 0, bj = 2; t < NKT; ++t) {
    char* rbase = (char*)lds + bi * BUFB;
    bf16x8 bfr[6];
#pragma unroll
    for (int j = 0; j < 6; ++j) {
      const int row = wn * 96 + (j << 4) + (l & 15);
      const int sr = row >> 1;
      bfr[j] = *(const bf16x8*)(rbase + 16384 + sr * 128 +
                                (((((row & 1) << 2) | (l >> 4)) ^ (sr & 7)) << 4));
    }
    bf16x8 af[4];
#pragma unroll
    for (int i = 0; i < 4; ++i) {
      const int row = (wm << 7) + (i << 4) + (l & 15);
      const int sr = row >> 1;
      af[i] = *(const bf16x8*)(rbase + sr * 128 +
                               (((((row & 1) << 2) | (l >> 4)) ^ (sr & 7)) << 4));
    }
    if (t + 2 < NKT) STAGE(t + 2, (char*)lds + bj * BUFB);
    asm volatile("s_waitcnt lgkmcnt(0)" ::: "memory");
    __builtin_amdgcn_sched_barrier(0);
    __builtin_amdgcn_s_setprio(1);
#pragma unroll
    for (int i = 0; i < 4; ++i)
#pragma unroll
      for (int j = 0; j < 6; ++j)
        acc[i][j] = mfma16(af[i], bfr[j], acc[i][j]);
    __builtin_amdgcn_s_setprio(0);
#pragma unroll
    for (int i = 0; i < 4; ++i) {  // A frag-rows 4..7
      const int row = (wm << 7) + 64 + (i << 4) + (l & 15);
      const int sr = row >> 1;
      af[i] = *(const bf16x8*)(rbase + sr * 128 +
                               (((((row & 1) << 2) | (l >> 4)) ^ (sr & 7)) << 4));
    }
    asm volatile("s_waitcnt lgkmcnt(0)" ::: "memory");
    __builtin_amdgcn_sched_barrier(0);
    __builtin_amdgcn_s_setprio(1);
#pragma unroll
    for (int i = 0; i < 4; ++i)
#pragma unroll
      for (int j = 0; j < 6; ++j)
        acc[4 + i][j] = mfma16(af[i], bfr[j], acc[4 + i][j]);
    __builtin_amdgcn_s_setprio(0);
    if (t + 2 < NKT) {
      asm volatile("s_waitcnt vmcnt(5)" ::: "memory");
    } else if (t + 2 == NKT) {
      asm volatile("s_waitcnt vmcnt(0)" ::: "memory");
    }
    __builtin_amdgcn_sched_barrier(0);
    __builtin_amdgcn_s_barrier();
    bi = (bi == 2) ? 0 : bi + 1;
    bj = (bj == 2) ? 0 : bj + 1;
  }

  // epilogue: frag (i,j): m = m0+wm*128+i*16+(l>>4)*4+r, nl = n0+wn*96+j*16+(l&15)
#pragma unroll
  for (int i = 0; i < 8; ++i)
#pragma unroll
    for (int j = 0; j < 6; ++j) {
      const int nl = n0 + wn * 96 + (j << 4) + (l & 15);
      const int which = nl >> 11;
      const int h = (nl >> 7) & 15, d = nl & 127;
      if (which < 2) {
        bf16* dst = which ? k_out : q_out;
#pragma unroll
        for (int r = 0; r < 4; ++r) {
          const int m = m0 + (wm << 7) + (i << 4) + ((l >> 4) << 2) + r;
          const int b_ = m >> 11, s = m & 2047;
          dst[(((size_t)((b_ << 4) | h)) * 2048 + s) * 128 + d] = (bf16)acc[i][j][r];
        }
      } else {
        const int sb = m0 + (wm << 7) + (i << 4) + ((l >> 4) << 2);
        const int b_ = sb >> 11, s = sb & 2047;
        bf16x4 vv;
#pragma unroll
        for (int r = 0; r < 4; ++r) vv[r] = (bf16)acc[i][j][r];
        *(bf16x4*)(v_out + ((size_t)((b_ << 4) | h) << 18) + ((size_t)d << 11) + s) = vv;
      }
    }
}

// ---------------- 128x128 BK=32 triple-buffer GEMM (out-proj), f32 out -------
// 4 waves (2x2), per-wave 64x64 (acc 64 regs). Grid 512 -> ~3 blocks/CU
// co-resident (cross-block MFMA/mem overlap). vmcnt(4) staging FIFO.
template <int NTN>  // NTN = N/128 = 16
__global__ __launch_bounds__(256, 2) void gemm_o(const bf16* __restrict__ A,
                                                 const bf16* __restrict__ Bt,
                                                 float* __restrict__ f_out) {
  constexpr int K = 2048, NKT = 64;
  constexpr int BUFB = 16384;  // A 8192 + B 8192
  __shared__ char lds[3 * BUFB];  // 48 KiB
  const int nwg = 32 * NTN;  // 512
  const int id = blockIdx.x;
  const int swz = (id & 7) * (nwg >> 3) + (id >> 3);
  const int bx = swz % NTN, by = swz / NTN;
  const int m0 = by << 7, n0 = bx << 7;
  const int tid = threadIdx.x, w = tid >> 6, l = tid & 63;  // w in 0..3
  const int wm = w >> 1, wn = w & 1;
  const int lsl = (l & 7) ^ ((l >> 3) & 7);
  const int srow = ((l >> 3) << 1) + (lsl >> 2);
  const int scol = (lsl & 3) << 3;

  auto STAGE = [&](int t, char* base) {
    const int k0 = t << 5;
#pragma unroll
    for (int c = 0; c < 2; ++c) {  // 4 waves x 16 rows x 2 = 128 rows each mat
      const int row = (c << 6) + (w << 4) + srow;
      gll16(A + (size_t)(m0 + row) * K + k0 + scol, base + (c << 12) + (w << 10));
      gll16(Bt + (size_t)(n0 + row) * K + k0 + scol, base + 8192 + (c << 12) + (w << 10));
    }
  };

  f32x4 acc[4][4] = {};

  STAGE(0, (char*)lds);
  STAGE(1, (char*)lds + BUFB);
  asm volatile("s_waitcnt vmcnt(4)" ::: "memory");
  __builtin_amdgcn_s_barrier();

#pragma unroll 1
  for (int t = 0, bi = 0, bj = 2; t < NKT; ++t) {
    char* rbase = (char*)lds + bi * BUFB;
    bf16x8 af[4], bfr[4];
#pragma unroll
    for (int i = 0; i < 4; ++i) {
      const int row = (wm << 6) + (i << 4) + (l & 15);
      const int sr = row >> 1;
      af[i] = *(const bf16x8*)(rbase + sr * 128 +
                               (((((row & 1) << 2) | (l >> 4)) ^ (sr & 7)) << 4));
    }
#pragma unroll
    for (int j = 0; j < 4; ++j) {
      const int row = (wn << 6) + (j << 4) + (l & 15);
      const int sr = row >> 1;
      bfr[j] = *(const bf16x8*)(rbase + 8192 + sr * 128 +
                                (((((row & 1) << 2) | (l >> 4)) ^ (sr & 7)) << 4));
    }
    if (t + 2 < NKT) STAGE(t + 2, (char*)lds + bj * BUFB);
    asm volatile("s_waitcnt lgkmcnt(0)" ::: "memory");
    __builtin_amdgcn_sched_barrier(0);
    __builtin_amdgcn_s_setprio(1);
#pragma unroll
    for (int i = 0; i < 4; ++i)
#pragma unroll
      for (int j = 0; j < 4; ++j)
        acc[i][j] = mfma16(af[i], bfr[j], acc[i][j]);
    __builtin_amdgcn_s_setprio(0);
    if (t + 2 < NKT) {
      asm volatile("s_waitcnt vmcnt(4)" ::: "memory");
    } else if (t + 2 == NKT) {
      asm volatile("s_waitcnt vmcnt(0)" ::: "memory");
    }
    __builtin_amdgcn_sched_barrier(0);
    __builtin_amdgcn_s_barrier();
    bi = (bi == 2) ? 0 : bi + 1;
    bj = (bj == 2) ? 0 : bj + 1;
  }

#pragma unroll
  for (int i = 0; i < 4; ++i)
#pragma unroll
    for (int j = 0; j < 4; ++j)
#pragma unroll
      for (int r = 0; r < 4; ++r) {
        const int m = m0 + (wm << 6) + (i << 4) + ((l >> 4) << 2) + r;
        const int n = n0 + (wn << 6) + (j << 4) + (l & 15);
        f_out[(size_t)m * 2048 + n] = acc[i][j][r];
      }
}

// ---------------- causal flash attention, swapped-operand 32x32 ----------------
// grid 512 = B*H*16 q-tiles; 4 waves x QBLK=32 rows = QB 128; KVBLK=64.
// Double-buffered K/V: next tile's 8 gll16 issued BEFORE compute; setprio.
__global__ __launch_bounds__(256, 2) void attn_kernel(const bf16* __restrict__ Qb,
                                                      const bf16* __restrict__ Kb,
                                                      const bf16* __restrict__ Vt,
                                                      bf16* __restrict__ Ao) {
  constexpr int S = 2048;
  __shared__ bf16 Ks[2][64 * 128];
  __shared__ bf16 Vs[2][128 * 64];
  const int idx = blockIdx.x;
  const int bh = idx >> 4;
  int qt = idx & 15;
  if (idx & 256) qt = 15 - qt;
  const int q0 = qt << 7;
  const int tid = threadIdx.x, w = tid >> 6, l = tid & 63;
  const int hi = l >> 5;
  const bf16* Qp = Qb + ((size_t)bh << 18);
  const bf16* Kp = Kb + ((size_t)bh << 18);
  const bf16* Vp = Vt + ((size_t)bh << 18);

  auto STAGE_KV = [&](int kv0, int bufi) {
    char* Kbase = (char*)Ks + (bufi << 14);
    char* Vbase = (char*)Vs + (bufi << 14);
#pragma unroll
    for (int i = 0; i < 4; ++i) {
      const int rk = (w << 4) + (i << 2) + (l >> 4);
      gll16(Kp + ((size_t)(kv0 + rk) << 7) + (((l & 15) ^ (rk & 7)) << 3),
            Kbase + (w << 12) + (i << 10));
      const int rv = (w << 5) + (i << 3) + (l >> 3);
      gll16(Vp + (size_t)rv * S + kv0 + (((l & 7) ^ (rv & 7)) << 3),
            Vbase + (w << 12) + (i << 10));
    }
  };

  bf16x8 qf[8];
#pragma unroll
  for (int kt = 0; kt < 8; ++kt)
    qf[kt] = *(const bf16x8*)(Qp + ((size_t)(q0 + (w << 5) + (l & 31)) << 7) + (kt << 4) + (hi << 3));

  f32x16 o[4] = {};
  float mrun = -3e38f, lrun = 0.f;

  const int qminw = q0 + (w << 5);
  const int qmaxw = qminw + 31;
  const int kv_end = q0 + 128;

  STAGE_KV(0, 0);
  __syncthreads();

  int bufi = 0;
#pragma unroll 1
  for (int kv0 = 0; kv0 < kv_end; kv0 += 64, bufi ^= 1) {
    if (kv0 + 64 < kv_end) STAGE_KV(kv0 + 64, bufi ^ 1);
    if (kv0 <= qmaxw) {
      const char* Kbase = (const char*)Ks + (bufi << 14);
      const char* Vbase = (const char*)Vs + (bufi << 14);
      f32x16 sc0 = {}, sc1 = {};
      __builtin_amdgcn_s_setprio(1);
#pragma unroll
      for (int kt = 0; kt < 8; ++kt) {
        const int rk0 = l & 31;
        const int coff = ((kt << 5) + (hi << 4));
        bf16x8 k0 = *(const bf16x8*)(Kbase + (rk0 << 8) + (coff ^ ((rk0 & 7) << 4)));
        bf16x8 k1 = *(const bf16x8*)(Kbase + ((rk0 + 32) << 8) + (coff ^ ((rk0 & 7) << 4)));
        sc0 = mfma32(k0, qf[kt], sc0);
        sc1 = mfma32(k1, qf[kt], sc1);
      }
      __builtin_amdgcn_s_setprio(0);
      if (kv0 + 63 > qminw) {
        const int qg = qminw + (l & 31);
#pragma unroll
        for (int r = 0; r < 16; ++r) {
          const int kvr = kv0 + (r & 3) + ((r >> 2) << 3) + (hi << 2);
          if (kvr > qg) sc0[r] = -3e38f;
          if (kvr + 32 > qg) sc1[r] = -3e38f;
        }
      }
      float mx = -3e38f;
#pragma unroll
      for (int r = 0; r < 16; ++r) mx = fmaxf(mx, fmaxf(sc0[r], sc1[r]));
      mx = fmaxf(mx, __shfl_xor(mx, 32));
      const float mnew = fmaxf(mrun, mx);
      if (!__all(mx <= mrun)) {
        const float alpha = exp2f(mrun - mnew);
        lrun *= alpha;
#pragma unroll
        for (int dt = 0; dt < 4; ++dt) o[dt] *= alpha;
      }
      mrun = mnew;
      float ps = 0.f;
#pragma unroll
      for (int r = 0; r < 16; ++r) {
        sc0[r] = exp2f(sc0[r] - mnew); ps += sc0[r];
        sc1[r] = exp2f(sc1[r] - mnew); ps += sc1[r];
      }
      ps += __shfl_xor(ps, 32);
      lrun += ps;
#pragma unroll
      for (int ks = 0; ks < 4; ++ks) {
        const f32x16& s = (ks & 2) ? sc1 : sc0;
        const int rb = (ks & 1) << 3;
        int pa_ = pack2(s[rb + 0], s[rb + 1]);
        int pb_ = pack2(s[rb + 2], s[rb + 3]);
        int pc_ = pack2(s[rb + 4], s[rb + 5]);
        int pd_ = pack2(s[rb + 6], s[rb + 7]);
        int sa = __shfl_xor(pa_, 32), sb = __shfl_xor(pb_, 32);
        int sc_ = __shfl_xor(pc_, 32), sd = __shfl_xor(pd_, 32);
        i32x4 pi;
        pi[0] = hi ? sc_ : pa_;
        pi[1] = hi ? sd : pb_;
        pi[2] = hi ? pc_ : sa;
        pi[3] = hi ? pd_ : sb;
        const bf16x8 pf = __builtin_bit_cast(bf16x8, pi);
        __builtin_amdgcn_s_setprio(1);
#pragma unroll
        for (int dt = 0; dt < 4; ++dt) {
          const int rd = (dt << 5) + (l & 31);
          const bf16x8 vf = *(const bf16x8*)(Vbase + (rd << 7) +
                                             (((ks << 5) + (hi << 4)) ^ ((rd & 7) << 4)));
          o[dt] = mfma32(vf, pf, o[dt]);
        }
        __builtin_amdgcn_s_setprio(0);
      }
    }
    __syncthreads();
  }
  const float rinv = 1.0f / lrun;
  const int b = bh >> 4, h = bh & 15;
  const int qg = q0 + (w << 5) + (l & 31);
  bf16* Arow = Ao + (((size_t)(b * S + qg)) << 11) + (h << 7);
#pragma unroll
  for (int dt = 0; dt < 4; ++dt)
#pragma unroll
    for (int g = 0; g < 4; ++g) {
      bf16x4 ov;
#pragma unroll
      for (int r = 0; r < 4; ++r) ov[r] = (bf16)(o[dt][(g << 2) + r] * rinv);
      *(bf16x4*)(Arow + (dt << 5) + (g << 3) + (hi << 2)) = ov;
    }
}

// ---------------- launch ----------------
extern "C" void kernel_launch(void* const* d_in, const int* in_sizes, int n_in,
                              void* d_out, int out_size, void* d_ws, size_t ws_size,
                              hipStream_t stream) {
  const float* x = (const float*)d_in[0];      // [2,2048,2048]
  const float* w_qkv = (const float*)d_in[1];  // [6144,2048]
  const float* w_o = (const float*)d_in[2];    // [2048,2048]
  float* out = (float*)d_out;                  // [2,2048,2048] f32
  char* ws = (char*)d_ws;

  bf16* xb    = (bf16*)(ws);
  bf16* wqkvb = (bf16*)(ws + (16ull << 20));
  bf16* wob   = (bf16*)(ws + (40ull << 20));
  bf16* Qb    = (bf16*)(ws + (48ull << 20));
  bf16* Kb    = (bf16*)(ws + (64ull << 20));
  bf16* Vt    = (bf16*)(ws + (80ull << 20));
  bf16* Ao    = (bf16*)(ws + (96ull << 20));
  float* ctab = (float*)(ws + (112ull << 20));
  float* stab = (float*)(ws + (113ull << 20));

  cvt_f32_bf16<<<4096, 256, 0, stream>>>(x, xb, 2 * 2048 * 2048);
  cvt_f32_bf16<<<6144, 256, 0, stream>>>(w_qkv, wqkvb, 6144 * 2048);
  cvt_f32_bf16<<<2048, 256, 0, stream>>>(w_o, wob, 2048 * 2048);
  rope_table<<<512, 256, 0, stream>>>(ctab, stab);
  gemm384<<<256, 512, 0, stream>>>(xb, wqkvb, Qb, Kb, Vt);
  rope_apply<<<4096, 256, 0, stream>>>(Qb, Kb, ctab, stab);
  attn_kernel<<<512, 256, 0, stream>>>(Qb, Kb, Vt, Ao);
  gemm_o<16><<<512, 256, 0, stream>>>(Ao, wob, out);
}

// Round 11
// 250.002 us; speedup vs baseline: 1.3031x; 1.0330x over previous
//
#include <hip/hip_runtime.h>
#include <hip/hip_bf16.h>

// SimpleAttention fused block on MI355X (gfx950), bf16 MFMA pipeline.
// B=2, S=2048, D_MODEL=2048, H=16, DK=128.
//
// R11: (a) 3x cvt + rope_table fused into one segmented prep_all kernel;
//      (b) attn XCD-chunked swizzle (4 bh per XCD L2) with flip-pairing
//          preserved (flip on swz bit5 so co-resident CU pairs sum 17 tiles);
//      (c) attn P-pack via v_cvt_pk_bf16_f32 (T12 primitive).
//      gemm384 (96us, 46% MfmaUtil - structure plateau) and gemm_o unchanged.
//
// ws layout (bytes):          size
//  xb      [4096,2048] bf16    16M @ 0
//  wqkvb   [6144,2048] bf16    24M @ 16M
//  wob     [2048,2048] bf16     8M @ 40M
//  Qb  [B,H,S,128] bf16        16M @ 48M
//  Kb  [B,H,S,128] bf16        16M @ 64M
//  Vt  [B,H,128,S] bf16        16M @ 80M
//  Ao  [B,S,2048]  bf16        16M @ 96M
//  ctab [2048,64] f32         512K @ 112M
//  stab [2048,64] f32         512K @ 113M

typedef __bf16 bf16;
typedef __bf16 bf16x4 __attribute__((ext_vector_type(4)));
typedef __bf16 bf16x8 __attribute__((ext_vector_type(8)));
typedef float f32x4 __attribute__((ext_vector_type(4)));
typedef float f32x16 __attribute__((ext_vector_type(16)));
typedef int i32x4 __attribute__((ext_vector_type(4)));

#define DEV __device__ __forceinline__

DEV void gll16(const void* g, void* lds_base_wave_uniform) {
  __builtin_amdgcn_global_load_lds((const __attribute__((address_space(1))) void*)g,
                                   (__attribute__((address_space(3))) void*)lds_base_wave_uniform,
                                   16, 0, 0);
}

DEV f32x4 mfma16(bf16x8 a, bf16x8 b, f32x4 c) {
  return __builtin_amdgcn_mfma_f32_16x16x32_bf16(a, b, c, 0, 0, 0);
}
DEV f32x16 mfma32(bf16x8 a, bf16x8 b, f32x16 c) {
  return __builtin_amdgcn_mfma_f32_32x32x16_bf16(a, b, c, 0, 0, 0);
}

DEV int cvtpk(float lo, float hi) {  // {hi:bf16(hi), lo:bf16(lo)}
  int r;
  asm("v_cvt_pk_bf16_f32 %0, %1, %2" : "=v"(r) : "v"(lo), "v"(hi));
  return r;
}

// ---------------- fused prep: 3x f32->bf16 cvt + rope tables ----------------
// blocks [0,4096): x -> xb ; [4096,10240): w_qkv -> wqkvb ;
// [10240,12288): w_o -> wob ; [12288,12800): rope tables.
__global__ __launch_bounds__(256) void prep_all(const float* __restrict__ x,
                                                const float* __restrict__ wqkv,
                                                const float* __restrict__ wo,
                                                bf16* __restrict__ xb,
                                                bf16* __restrict__ wqkvb,
                                                bf16* __restrict__ wob,
                                                float* __restrict__ ctab,
                                                float* __restrict__ stab) {
  const int b = blockIdx.x;
  if (b < 12288) {
    const float* in;
    bf16* out;
    int bb = b;
    if (b < 4096) {
      in = x; out = xb;
    } else if (b < 10240) {
      in = wqkv; out = wqkvb; bb -= 4096;
    } else {
      in = wo; out = wob; bb -= 10240;
    }
    const int i = (bb * 256 + threadIdx.x) << 3;
    float4 a = *(const float4*)(in + i);
    float4 c = *(const float4*)(in + i + 4);
    bf16x8 o;
    o[0] = (bf16)a.x; o[1] = (bf16)a.y; o[2] = (bf16)a.z; o[3] = (bf16)a.w;
    o[4] = (bf16)c.x; o[5] = (bf16)c.y; o[6] = (bf16)c.z; o[7] = (bf16)c.w;
    *(bf16x8*)(out + i) = o;
  } else {
    // rope tables: freq[j] = 10000^(-j/63)  (linspace(0,1,64) inclusive!)
    const int id = (b - 12288) * 256 + threadIdx.x;  // 2048*64
    const int s = id >> 6, j = id & 63;
    float freq = powf(10000.0f, -(float)j / 63.0f);
    float th = (float)s * freq;
    ctab[id] = cosf(th);
    stab[id] = sinf(th);
  }
}

// ---------------- in-place rope on Qb (with scale) and Kb, bf16x8 ----------------
__global__ __launch_bounds__(256) void rope_apply(bf16* __restrict__ Qb, bf16* __restrict__ Kb,
                                                  const float* __restrict__ ctab,
                                                  const float* __restrict__ stab) {
  const float QSCALE = 0.08838834764831845f * 1.4426950408889634f;
  int id = blockIdx.x * 256 + threadIdx.x;  // 2 * 32*2048*8
  const int half = 32 * 2048 * 8;
  bf16* P = (id < half) ? Qb : Kb;
  const float scale = (id < half) ? QSCALE : 1.0f;
  int t = (id < half) ? id : id - half;
  const int d0 = (t & 7) << 3;        // 8 rotary pairs per thread
  const int s = (t >> 3) & 2047;
  const int bh = t >> 14;
  bf16* p = P + (((size_t)bh * 2048 + s) << 7);
  bf16x8 x1 = *(bf16x8*)(p + d0);
  bf16x8 x2 = *(bf16x8*)(p + d0 + 64);
  float4 ca = *(const float4*)(ctab + (s << 6) + d0);
  float4 cb = *(const float4*)(ctab + (s << 6) + d0 + 4);
  float4 sa = *(const float4*)(stab + (s << 6) + d0);
  float4 sb = *(const float4*)(stab + (s << 6) + d0 + 4);
  const float c[8] = {ca.x, ca.y, ca.z, ca.w, cb.x, cb.y, cb.z, cb.w};
  const float sn[8] = {sa.x, sa.y, sa.z, sa.w, sb.x, sb.y, sb.z, sb.w};
  bf16x8 y1, y2;
#pragma unroll
  for (int j = 0; j < 8; ++j) {
    const float a = (float)x1[j], b = (float)x2[j];
    y1[j] = (bf16)((a * c[j] - b * sn[j]) * scale);
    y2[j] = (bf16)((a * sn[j] + b * c[j]) * scale);
  }
  *(bf16x8*)(p + d0) = y1;
  *(bf16x8*)(p + d0 + 64) = y2;
}

// ---------------- 256x384 BK=32 triple-buffer GEMM (QKV): C = A * Bt^T -------
// R8 structure (96us, MfmaUtil 46%): two 24-MFMA clusters with A-frag reload
// between them (keeps live frag set small; fusing all 14 frags spilled in R9).
__global__ __launch_bounds__(512, 2) void gemm384(const bf16* __restrict__ A,
                                                  const bf16* __restrict__ Bt,
                                                  bf16* __restrict__ q_out,
                                                  bf16* __restrict__ k_out,
                                                  bf16* __restrict__ v_out) {
  constexpr int K = 2048, NKT = 64;
  constexpr int BUFB = 40960;  // A 16384 + B 24576
  __shared__ char lds[3 * BUFB];  // 120 KiB
  const int id = blockIdx.x;
  const int swz = (id & 7) * 32 + (id >> 3);  // XCD swizzle (256 blocks)
  const int bx = swz & 15, by = swz >> 4;
  const int m0 = by << 8;      // 256-row M tile
  const int n0 = bx * 384;     // 384-col N tile
  const int tid = threadIdx.x, w = tid >> 6, l = tid & 63;
  const int wm = w >> 2, wn = w & 3;
  // staging decode (verified 0 bank conflicts)
  const int lsl = (l & 7) ^ ((l >> 3) & 7);
  const int srow = ((l >> 3) << 1) + (lsl >> 2);
  const int scol = (lsl & 3) << 3;

  auto STAGE = [&](int t, char* base) {
    const int k0 = t << 5;
#pragma unroll
    for (int c = 0; c < 2; ++c) {  // A: 256 rows = 2 issues
      const int row = (c << 7) + (w << 4) + srow;
      gll16(A + (size_t)(m0 + row) * K + k0 + scol, base + (c << 13) + (w << 10));
    }
#pragma unroll
    for (int c = 0; c < 3; ++c) {  // B: 384 rows = 3 issues
      const int row = (c << 7) + (w << 4) + srow;
      gll16(Bt + (size_t)(n0 + row) * K + k0 + scol, base + 16384 + (c << 13) + (w << 10));
    }
  };

  f32x4 acc[8][6] = {};

  STAGE(0, (char*)lds);
  STAGE(1, (char*)lds + BUFB);
  asm volatile("s_waitcnt vmcnt(5)" ::: "memory");
  __builtin_amdgcn_s_barrier();

#pragma unroll 1
  for (int t = 0, bi = 0, bj = 2; t < NKT; ++t) {
    char* rbase = (char*)lds + bi * BUFB;
    bf16x8 bfr[6];
#pragma unroll
    for (int j = 0; j < 6; ++j) {
      const int row = wn * 96 + (j << 4) + (l & 15);
      const int sr = row >> 1;
      bfr[j] = *(const bf16x8*)(rbase + 16384 + sr * 128 +
                                (((((row & 1) << 2) | (l >> 4)) ^ (sr & 7)) << 4));
    }
    bf16x8 af[4];
#pragma unroll
    for (int i = 0; i < 4; ++i) {
      const int row = (wm << 7) + (i << 4) + (l & 15);
      const int sr = row >> 1;
      af[i] = *(const bf16x8*)(rbase + sr * 128 +
                               (((((row & 1) << 2) | (l >> 4)) ^ (sr & 7)) << 4));
    }
    if (t + 2 < NKT) STAGE(t + 2, (char*)lds + bj * BUFB);
    asm volatile("s_waitcnt lgkmcnt(0)" ::: "memory");
    __builtin_amdgcn_sched_barrier(0);
    __builtin_amdgcn_s_setprio(1);
#pragma unroll
    for (int i = 0; i < 4; ++i)
#pragma unroll
      for (int j = 0; j < 6; ++j)
        acc[i][j] = mfma16(af[i], bfr[j], acc[i][j]);
    __builtin_amdgcn_s_setprio(0);
#pragma unroll
    for (int i = 0; i < 4; ++i) {  // A frag-rows 4..7
      const int row = (wm << 7) + 64 + (i << 4) + (l & 15);
      const int sr = row >> 1;
      af[i] = *(const bf16x8*)(rbase + sr * 128 +
                               (((((row & 1) << 2) | (l >> 4)) ^ (sr & 7)) << 4));
    }
    asm volatile("s_waitcnt lgkmcnt(0)" ::: "memory");
    __builtin_amdgcn_sched_barrier(0);
    __builtin_amdgcn_s_setprio(1);
#pragma unroll
    for (int i = 0; i < 4; ++i)
#pragma unroll
      for (int j = 0; j < 6; ++j)
        acc[4 + i][j] = mfma16(af[i], bfr[j], acc[4 + i][j]);
    __builtin_amdgcn_s_setprio(0);
    if (t + 2 < NKT) {
      asm volatile("s_waitcnt vmcnt(5)" ::: "memory");
    } else if (t + 2 == NKT) {
      asm volatile("s_waitcnt vmcnt(0)" ::: "memory");
    }
    __builtin_amdgcn_sched_barrier(0);
    __builtin_amdgcn_s_barrier();
    bi = (bi == 2) ? 0 : bi + 1;
    bj = (bj == 2) ? 0 : bj + 1;
  }

  // epilogue: frag (i,j): m = m0+wm*128+i*16+(l>>4)*4+r, nl = n0+wn*96+j*16+(l&15)
#pragma unroll
  for (int i = 0; i < 8; ++i)
#pragma unroll
    for (int j = 0; j < 6; ++j) {
      const int nl = n0 + wn * 96 + (j << 4) + (l & 15);
      const int which = nl >> 11;
      const int h = (nl >> 7) & 15, d = nl & 127;
      if (which < 2) {
        bf16* dst = which ? k_out : q_out;
#pragma unroll
        for (int r = 0; r < 4; ++r) {
          const int m = m0 + (wm << 7) + (i << 4) + ((l >> 4) << 2) + r;
          const int b_ = m >> 11, s = m & 2047;
          dst[(((size_t)((b_ << 4) | h)) * 2048 + s) * 128 + d] = (bf16)acc[i][j][r];
        }
      } else {
        const int sb = m0 + (wm << 7) + (i << 4) + ((l >> 4) << 2);
        const int b_ = sb >> 11, s = sb & 2047;
        bf16x4 vv;
#pragma unroll
        for (int r = 0; r < 4; ++r) vv[r] = (bf16)acc[i][j][r];
        *(bf16x4*)(v_out + ((size_t)((b_ << 4) | h) << 18) + ((size_t)d << 11) + s) = vv;
      }
    }
}

// ---------------- 128x128 BK=32 triple-buffer GEMM (out-proj), f32 out -------
template <int NTN>  // NTN = N/128 = 16
__global__ __launch_bounds__(256, 2) void gemm_o(const bf16* __restrict__ A,
                                                 const bf16* __restrict__ Bt,
                                                 float* __restrict__ f_out) {
  constexpr int K = 2048, NKT = 64;
  constexpr int BUFB = 16384;  // A 8192 + B 8192
  __shared__ char lds[3 * BUFB];  // 48 KiB
  const int nwg = 32 * NTN;  // 512
  const int id = blockIdx.x;
  const int swz = (id & 7) * (nwg >> 3) + (id >> 3);
  const int bx = swz % NTN, by = swz / NTN;
  const int m0 = by << 7, n0 = bx << 7;
  const int tid = threadIdx.x, w = tid >> 6, l = tid & 63;  // w in 0..3
  const int wm = w >> 1, wn = w & 1;
  const int lsl = (l & 7) ^ ((l >> 3) & 7);
  const int srow = ((l >> 3) << 1) + (lsl >> 2);
  const int scol = (lsl & 3) << 3;

  auto STAGE = [&](int t, char* base) {
    const int k0 = t << 5;
#pragma unroll
    for (int c = 0; c < 2; ++c) {
      const int row = (c << 6) + (w << 4) + srow;
      gll16(A + (size_t)(m0 + row) * K + k0 + scol, base + (c << 12) + (w << 10));
      gll16(Bt + (size_t)(n0 + row) * K + k0 + scol, base + 8192 + (c << 12) + (w << 10));
    }
  };

  f32x4 acc[4][4] = {};

  STAGE(0, (char*)lds);
  STAGE(1, (char*)lds + BUFB);
  asm volatile("s_waitcnt vmcnt(4)" ::: "memory");
  __builtin_amdgcn_s_barrier();

#pragma unroll 1
  for (int t = 0, bi = 0, bj = 2; t < NKT; ++t) {
    char* rbase = (char*)lds + bi * BUFB;
    bf16x8 af[4], bfr[4];
#pragma unroll
    for (int i = 0; i < 4; ++i) {
      const int row = (wm << 6) + (i << 4) + (l & 15);
      const int sr = row >> 1;
      af[i] = *(const bf16x8*)(rbase + sr * 128 +
                               (((((row & 1) << 2) | (l >> 4)) ^ (sr & 7)) << 4));
    }
#pragma unroll
    for (int j = 0; j < 4; ++j) {
      const int row = (wn << 6) + (j << 4) + (l & 15);
      const int sr = row >> 1;
      bfr[j] = *(const bf16x8*)(rbase + 8192 + sr * 128 +
                                (((((row & 1) << 2) | (l >> 4)) ^ (sr & 7)) << 4));
    }
    if (t + 2 < NKT) STAGE(t + 2, (char*)lds + bj * BUFB);
    asm volatile("s_waitcnt lgkmcnt(0)" ::: "memory");
    __builtin_amdgcn_sched_barrier(0);
    __builtin_amdgcn_s_setprio(1);
#pragma unroll
    for (int i = 0; i < 4; ++i)
#pragma unroll
      for (int j = 0; j < 4; ++j)
        acc[i][j] = mfma16(af[i], bfr[j], acc[i][j]);
    __builtin_amdgcn_s_setprio(0);
    if (t + 2 < NKT) {
      asm volatile("s_waitcnt vmcnt(4)" ::: "memory");
    } else if (t + 2 == NKT) {
      asm volatile("s_waitcnt vmcnt(0)" ::: "memory");
    }
    __builtin_amdgcn_sched_barrier(0);
    __builtin_amdgcn_s_barrier();
    bi = (bi == 2) ? 0 : bi + 1;
    bj = (bj == 2) ? 0 : bj + 1;
  }

#pragma unroll
  for (int i = 0; i < 4; ++i)
#pragma unroll
    for (int j = 0; j < 4; ++j)
#pragma unroll
      for (int r = 0; r < 4; ++r) {
        const int m = m0 + (wm << 6) + (i << 4) + ((l >> 4) << 2) + r;
        const int n = n0 + (wn << 6) + (j << 4) + (l & 15);
        f_out[(size_t)m * 2048 + n] = acc[i][j][r];
      }
}

// ---------------- causal flash attention, swapped-operand 32x32 ----------------
// grid 512; XCD-chunked swizzle: XCD x gets swz [x*64,(x+1)*64) = 4 bh (4MB K/V
// fits one L2). Flip-pairing on swz bit5: co-resident CU pairs sum 17 tiles.
// 4 waves x QBLK=32 rows = QB 128; KVBLK=64; dbuf prefetch-before-compute.
__global__ __launch_bounds__(256, 2) void attn_kernel(const bf16* __restrict__ Qb,
                                                      const bf16* __restrict__ Kb,
                                                      const bf16* __restrict__ Vt,
                                                      bf16* __restrict__ Ao) {
  constexpr int S = 2048;
  __shared__ bf16 Ks[2][64 * 128];
  __shared__ bf16 Vs[2][128 * 64];
  const int id = blockIdx.x;
  const int swz = (id & 7) * 64 + (id >> 3);  // 512 blocks, 64 per XCD
  const int bh = swz >> 4;
  int qt = swz & 15;
  if ((swz >> 5) & 1) qt = 15 - qt;  // pair rounds within a CU: qt + (15-qt)
  const int q0 = qt << 7;
  const int tid = threadIdx.x, w = tid >> 6, l = tid & 63;
  const int hi = l >> 5;
  const bf16* Qp = Qb + ((size_t)bh << 18);
  const bf16* Kp = Kb + ((size_t)bh << 18);
  const bf16* Vp = Vt + ((size_t)bh << 18);

  auto STAGE_KV = [&](int kv0, int bufi) {
    char* Kbase = (char*)Ks + (bufi << 14);
    char* Vbase = (char*)Vs + (bufi << 14);
#pragma unroll
    for (int i = 0; i < 4; ++i) {
      const int rk = (w << 4) + (i << 2) + (l >> 4);
      gll16(Kp + ((size_t)(kv0 + rk) << 7) + (((l & 15) ^ (rk & 7)) << 3),
            Kbase + (w << 12) + (i << 10));
      const int rv = (w << 5) + (i << 3) + (l >> 3);
      gll16(Vp + (size_t)rv * S + kv0 + (((l & 7) ^ (rv & 7)) << 3),
            Vbase + (w << 12) + (i << 10));
    }
  };

  bf16x8 qf[8];
#pragma unroll
  for (int kt = 0; kt < 8; ++kt)
    qf[kt] = *(const bf16x8*)(Qp + ((size_t)(q0 + (w << 5) + (l & 31)) << 7) + (kt << 4) + (hi << 3));

  f32x16 o[4] = {};
  float mrun = -3e38f, lrun = 0.f;

  const int qminw = q0 + (w << 5);
  const int qmaxw = qminw + 31;
  const int kv_end = q0 + 128;

  STAGE_KV(0, 0);
  __syncthreads();

  int bufi = 0;
#pragma unroll 1
  for (int kv0 = 0; kv0 < kv_end; kv0 += 64, bufi ^= 1) {
    if (kv0 + 64 < kv_end) STAGE_KV(kv0 + 64, bufi ^ 1);
    if (kv0 <= qmaxw) {
      const char* Kbase = (const char*)Ks + (bufi << 14);
      const char* Vbase = (const char*)Vs + (bufi << 14);
      f32x16 sc0 = {}, sc1 = {};
      __builtin_amdgcn_s_setprio(1);
#pragma unroll
      for (int kt = 0; kt < 8; ++kt) {
        const int rk0 = l & 31;
        const int coff = ((kt << 5) + (hi << 4));
        bf16x8 k0 = *(const bf16x8*)(Kbase + (rk0 << 8) + (coff ^ ((rk0 & 7) << 4)));
        bf16x8 k1 = *(const bf16x8*)(Kbase + ((rk0 + 32) << 8) + (coff ^ ((rk0 & 7) << 4)));
        sc0 = mfma32(k0, qf[kt], sc0);
        sc1 = mfma32(k1, qf[kt], sc1);
      }
      __builtin_amdgcn_s_setprio(0);
      if (kv0 + 63 > qminw) {
        const int qg = qminw + (l & 31);
#pragma unroll
        for (int r = 0; r < 16; ++r) {
          const int kvr = kv0 + (r & 3) + ((r >> 2) << 3) + (hi << 2);
          if (kvr > qg) sc0[r] = -3e38f;
          if (kvr + 32 > qg) sc1[r] = -3e38f;
        }
      }
      float mx = -3e38f;
#pragma unroll
      for (int r = 0; r < 16; ++r) mx = fmaxf(mx, fmaxf(sc0[r], sc1[r]));
      mx = fmaxf(mx, __shfl_xor(mx, 32));
      const float mnew = fmaxf(mrun, mx);
      if (!__all(mx <= mrun)) {
        const float alpha = exp2f(mrun - mnew);
        lrun *= alpha;
#pragma unroll
        for (int dt = 0; dt < 4; ++dt) o[dt] *= alpha;
      }
      mrun = mnew;
      float ps = 0.f;
#pragma unroll
      for (int r = 0; r < 16; ++r) {
        sc0[r] = exp2f(sc0[r] - mnew); ps += sc0[r];
        sc1[r] = exp2f(sc1[r] - mnew); ps += sc1[r];
      }
      ps += __shfl_xor(ps, 32);
      lrun += ps;
#pragma unroll
      for (int ks = 0; ks < 4; ++ks) {
        const f32x16& s = (ks & 2) ? sc1 : sc0;
        const int rb = (ks & 1) << 3;
        int pa_ = cvtpk(s[rb + 0], s[rb + 1]);
        int pb_ = cvtpk(s[rb + 2], s[rb + 3]);
        int pc_ = cvtpk(s[rb + 4], s[rb + 5]);
        int pd_ = cvtpk(s[rb + 6], s[rb + 7]);
        int sa = __shfl_xor(pa_, 32), sb = __shfl_xor(pb_, 32);
        int sc_ = __shfl_xor(pc_, 32), sd = __shfl_xor(pd_, 32);
        i32x4 pi;
        pi[0] = hi ? sc_ : pa_;
        pi[1] = hi ? sd : pb_;
        pi[2] = hi ? pc_ : sa;
        pi[3] = hi ? pd_ : sb;
        const bf16x8 pf = __builtin_bit_cast(bf16x8, pi);
        __builtin_amdgcn_s_setprio(1);
#pragma unroll
        for (int dt = 0; dt < 4; ++dt) {
          const int rd = (dt << 5) + (l & 31);
          const bf16x8 vf = *(const bf16x8*)(Vbase + (rd << 7) +
                                             (((ks << 5) + (hi << 4)) ^ ((rd & 7) << 4)));
          o[dt] = mfma32(vf, pf, o[dt]);
        }
        __builtin_amdgcn_s_setprio(0);
      }
    }
    __syncthreads();
  }
  const float rinv = 1.0f / lrun;
  const int b = bh >> 4, h = bh & 15;
  const int qg = q0 + (w << 5) + (l & 31);
  bf16* Arow = Ao + (((size_t)(b * S + qg)) << 11) + (h << 7);
#pragma unroll
  for (int dt = 0; dt < 4; ++dt)
#pragma unroll
    for (int g = 0; g < 4; ++g) {
      bf16x4 ov;
#pragma unroll
      for (int r = 0; r < 4; ++r) ov[r] = (bf16)(o[dt][(g << 2) + r] * rinv);
      *(bf16x4*)(Arow + (dt << 5) + (g << 3) + (hi << 2)) = ov;
    }
}

// ---------------- launch ----------------
extern "C" void kernel_launch(void* const* d_in, const int* in_sizes, int n_in,
                              void* d_out, int out_size, void* d_ws, size_t ws_size,
                              hipStream_t stream) {
  const float* x = (const float*)d_in[0];      // [2,2048,2048]
  const float* w_qkv = (const float*)d_in[1];  // [6144,2048]
  const float* w_o = (const float*)d_in[2];    // [2048,2048]
  float* out = (float*)d_out;                  // [2,2048,2048] f32
  char* ws = (char*)d_ws;

  bf16* xb    = (bf16*)(ws);
  bf16* wqkvb = (bf16*)(ws + (16ull << 20));
  bf16* wob   = (bf16*)(ws + (40ull << 20));
  bf16* Qb    = (bf16*)(ws + (48ull << 20));
  bf16* Kb    = (bf16*)(ws + (64ull << 20));
  bf16* Vt    = (bf16*)(ws + (80ull << 20));
  bf16* Ao    = (bf16*)(ws + (96ull << 20));
  float* ctab = (float*)(ws + (112ull << 20));
  float* stab = (float*)(ws + (113ull << 20));

  prep_all<<<12800, 256, 0, stream>>>(x, w_qkv, w_o, xb, wqkvb, wob, ctab, stab);
  gemm384<<<256, 512, 0, stream>>>(xb, wqkvb, Qb, Kb, Vt);
  rope_apply<<<4096, 256, 0, stream>>>(Qb, Kb, ctab, stab);
  attn_kernel<<<512, 256, 0, stream>>>(Qb, Kb, Vt, Ao);
  gemm_o<16><<<512, 256, 0, stream>>>(Ao, wob, out);
}

// Round 12
// 244.904 us; speedup vs baseline: 1.3302x; 1.0208x over previous
//
#include <hip/hip_runtime.h>
#include <hip/hip_bf16.h>

// SimpleAttention fused block on MI355X (gfx950), bf16 MFMA pipeline.
// B=2, S=2048, D_MODEL=2048, H=16, DK=128.
//
// R12: rope_apply kernel ELIMINATED.
//  - K-rope fused into gemm384 epilogue via B-frag permutation: wave wn owns,
//    per 128-col head-block, cols {wn*16..+15} U {wn*16+64..+79}, so rotary
//    pairs (d, d+64) live in the same lane (frags 2p / 2p+1); rope applied
//    from f32 acc (single bf16 rounding for K now).
//  - Q-rope fused into attn qf load (pairs qf[kt]/qf[kt+4]); QSCALE folded.
//
// ws layout (bytes):          size
//  xb      [4096,2048] bf16    16M @ 0
//  wqkvb   [6144,2048] bf16    24M @ 16M
//  wob     [2048,2048] bf16     8M @ 40M
//  Qb  [B,H,S,128] bf16        16M @ 48M   (raw, rope applied in attn)
//  Kb  [B,H,S,128] bf16        16M @ 64M   (roped by gemm384 epilogue)
//  Vt  [B,H,128,S] bf16        16M @ 80M
//  Ao  [B,S,2048]  bf16        16M @ 96M
//  ctab [2048,64] f32         512K @ 112M
//  stab [2048,64] f32         512K @ 113M

typedef __bf16 bf16;
typedef __bf16 bf16x4 __attribute__((ext_vector_type(4)));
typedef __bf16 bf16x8 __attribute__((ext_vector_type(8)));
typedef float f32x4 __attribute__((ext_vector_type(4)));
typedef float f32x16 __attribute__((ext_vector_type(16)));
typedef int i32x4 __attribute__((ext_vector_type(4)));

#define DEV __device__ __forceinline__

DEV void gll16(const void* g, void* lds_base_wave_uniform) {
  __builtin_amdgcn_global_load_lds((const __attribute__((address_space(1))) void*)g,
                                   (__attribute__((address_space(3))) void*)lds_base_wave_uniform,
                                   16, 0, 0);
}

DEV f32x4 mfma16(bf16x8 a, bf16x8 b, f32x4 c) {
  return __builtin_amdgcn_mfma_f32_16x16x32_bf16(a, b, c, 0, 0, 0);
}
DEV f32x16 mfma32(bf16x8 a, bf16x8 b, f32x16 c) {
  return __builtin_amdgcn_mfma_f32_32x32x16_bf16(a, b, c, 0, 0, 0);
}

DEV int cvtpk(float lo, float hi) {  // {hi:bf16(hi), lo:bf16(lo)}
  int r;
  asm("v_cvt_pk_bf16_f32 %0, %1, %2" : "=v"(r) : "v"(lo), "v"(hi));
  return r;
}

// ---------------- fused prep: 3x f32->bf16 cvt + rope tables ----------------
__global__ __launch_bounds__(256) void prep_all(const float* __restrict__ x,
                                                const float* __restrict__ wqkv,
                                                const float* __restrict__ wo,
                                                bf16* __restrict__ xb,
                                                bf16* __restrict__ wqkvb,
                                                bf16* __restrict__ wob,
                                                float* __restrict__ ctab,
                                                float* __restrict__ stab) {
  const int b = blockIdx.x;
  if (b < 12288) {
    const float* in;
    bf16* out;
    int bb = b;
    if (b < 4096) {
      in = x; out = xb;
    } else if (b < 10240) {
      in = wqkv; out = wqkvb; bb -= 4096;
    } else {
      in = wo; out = wob; bb -= 10240;
    }
    const int i = (bb * 256 + threadIdx.x) << 3;
    float4 a = *(const float4*)(in + i);
    float4 c = *(const float4*)(in + i + 4);
    bf16x8 o;
    o[0] = (bf16)a.x; o[1] = (bf16)a.y; o[2] = (bf16)a.z; o[3] = (bf16)a.w;
    o[4] = (bf16)c.x; o[5] = (bf16)c.y; o[6] = (bf16)c.z; o[7] = (bf16)c.w;
    *(bf16x8*)(out + i) = o;
  } else {
    // rope tables: freq[j] = 10000^(-j/63)  (linspace(0,1,64) inclusive!)
    const int id = (b - 12288) * 256 + threadIdx.x;  // 2048*64
    const int s = id >> 6, j = id & 63;
    float freq = powf(10000.0f, -(float)j / 63.0f);
    float th = (float)s * freq;
    ctab[id] = cosf(th);
    stab[id] = sinf(th);
  }
}

// ---------------- 256x384 BK=32 triple-buffer GEMM (QKV) + fused K-rope ------
// R8 schedule (two 24-MFMA clusters, counted vmcnt(5), triple buffer).
// B-frag permutation: frag j -> tile row (j>>1)*128 + (j&1)*64 + wn*16 + (l&15)
// so rotary pairs (d2, d2+64) are frags (2p, 2p+1) in the SAME lane.
__global__ __launch_bounds__(512, 2) void gemm384(const bf16* __restrict__ A,
                                                  const bf16* __restrict__ Bt,
                                                  bf16* __restrict__ q_out,
                                                  bf16* __restrict__ k_out,
                                                  bf16* __restrict__ v_out,
                                                  const float* __restrict__ ctab,
                                                  const float* __restrict__ stab) {
  constexpr int K = 2048, NKT = 64;
  constexpr int BUFB = 40960;  // A 16384 + B 24576
  __shared__ char lds[3 * BUFB];  // 120 KiB
  const int id = blockIdx.x;
  const int swz = (id & 7) * 32 + (id >> 3);  // XCD swizzle (256 blocks)
  const int bx = swz & 15, by = swz >> 4;
  const int m0 = by << 8;      // 256-row M tile
  const int n0 = bx * 384;     // 384-col N tile
  const int tid = threadIdx.x, w = tid >> 6, l = tid & 63;
  const int wm = w >> 2, wn = w & 3;
  // staging decode (verified 0 bank conflicts)
  const int lsl = (l & 7) ^ ((l >> 3) & 7);
  const int srow = ((l >> 3) << 1) + (lsl >> 2);
  const int scol = (lsl & 3) << 3;

  auto STAGE = [&](int t, char* base) {
    const int k0 = t << 5;
#pragma unroll
    for (int c = 0; c < 2; ++c) {  // A: 256 rows = 2 issues
      const int row = (c << 7) + (w << 4) + srow;
      gll16(A + (size_t)(m0 + row) * K + k0 + scol, base + (c << 13) + (w << 10));
    }
#pragma unroll
    for (int c = 0; c < 3; ++c) {  // B: 384 rows = 3 issues
      const int row = (c << 7) + (w << 4) + srow;
      gll16(Bt + (size_t)(n0 + row) * K + k0 + scol, base + 16384 + (c << 13) + (w << 10));
    }
  };

  f32x4 acc[8][6] = {};

  STAGE(0, (char*)lds);
  STAGE(1, (char*)lds + BUFB);
  asm volatile("s_waitcnt vmcnt(5)" ::: "memory");
  __builtin_amdgcn_s_barrier();

#pragma unroll 1
  for (int t = 0, bi = 0, bj = 2; t < NKT; ++t) {
    char* rbase = (char*)lds + bi * BUFB;
    bf16x8 bfr[6];
#pragma unroll
    for (int j = 0; j < 6; ++j) {
      // permuted: head-block j>>1, half (j&1)*64, cols wn*16..+15
      const int row = ((j >> 1) << 7) + ((j & 1) << 6) + (wn << 4) + (l & 15);
      const int sr = row >> 1;
      bfr[j] = *(const bf16x8*)(rbase + 16384 + sr * 128 +
                                (((((row & 1) << 2) | (l >> 4)) ^ (sr & 7)) << 4));
    }
    bf16x8 af[4];
#pragma unroll
    for (int i = 0; i < 4; ++i) {
      const int row = (wm << 7) + (i << 4) + (l & 15);
      const int sr = row >> 1;
      af[i] = *(const bf16x8*)(rbase + sr * 128 +
                               (((((row & 1) << 2) | (l >> 4)) ^ (sr & 7)) << 4));
    }
    if (t + 2 < NKT) STAGE(t + 2, (char*)lds + bj * BUFB);
    asm volatile("s_waitcnt lgkmcnt(0)" ::: "memory");
    __builtin_amdgcn_sched_barrier(0);
    __builtin_amdgcn_s_setprio(1);
#pragma unroll
    for (int i = 0; i < 4; ++i)
#pragma unroll
      for (int j = 0; j < 6; ++j)
        acc[i][j] = mfma16(af[i], bfr[j], acc[i][j]);
    __builtin_amdgcn_s_setprio(0);
#pragma unroll
    for (int i = 0; i < 4; ++i) {  // A frag-rows 4..7
      const int row = (wm << 7) + 64 + (i << 4) + (l & 15);
      const int sr = row >> 1;
      af[i] = *(const bf16x8*)(rbase + sr * 128 +
                               (((((row & 1) << 2) | (l >> 4)) ^ (sr & 7)) << 4));
    }
    asm volatile("s_waitcnt lgkmcnt(0)" ::: "memory");
    __builtin_amdgcn_sched_barrier(0);
    __builtin_amdgcn_s_setprio(1);
#pragma unroll
    for (int i = 0; i < 4; ++i)
#pragma unroll
      for (int j = 0; j < 6; ++j)
        acc[4 + i][j] = mfma16(af[i], bfr[j], acc[4 + i][j]);
    __builtin_amdgcn_s_setprio(0);
    if (t + 2 < NKT) {
      asm volatile("s_waitcnt vmcnt(5)" ::: "memory");
    } else if (t + 2 == NKT) {
      asm volatile("s_waitcnt vmcnt(0)" ::: "memory");
    }
    __builtin_amdgcn_sched_barrier(0);
    __builtin_amdgcn_s_barrier();
    bi = (bi == 2) ? 0 : bi + 1;
    bj = (bj == 2) ? 0 : bj + 1;
  }

  // epilogue: frag (i,j): m = m0+wm*128+i*16+(l>>4)*4+r;
  // col = n0 + (j>>1)*128 + (j&1)*64 + d2, d2 = wn*16+(l&15).
  // Head-blocks (128 cols) never straddle Q/K/V boundaries.
  const int d2 = (wn << 4) + (l & 15);
#pragma unroll
  for (int i = 0; i < 8; ++i) {
    const int mbase = m0 + (wm << 7) + (i << 4) + ((l >> 4) << 2);
    const int b_ = mbase >> 11, sbase = mbase & 2047;
    float cc[4], ss[4];
    if (((n0 + 256) >> 11) == 1 || (n0 >> 11) == 1) {  // any K head-block in tile
#pragma unroll
      for (int r = 0; r < 4; ++r) {
        cc[r] = ctab[((sbase + r) << 6) + d2];
        ss[r] = stab[((sbase + r) << 6) + d2];
      }
    }
#pragma unroll
    for (int p = 0; p < 3; ++p) {
      const int nb = n0 + (p << 7);
      const int which = nb >> 11;
      const int h = (nb >> 7) & 15;
      if (which == 0) {  // Q raw
        const size_t base = (((size_t)((b_ << 4) | h)) * 2048 + sbase) * 128;
#pragma unroll
        for (int r = 0; r < 4; ++r) {
          q_out[base + ((size_t)r << 7) + d2]      = (bf16)acc[i][2 * p][r];
          q_out[base + ((size_t)r << 7) + d2 + 64] = (bf16)acc[i][2 * p + 1][r];
        }
      } else if (which == 1) {  // K with fused rope (from f32 acc)
        const size_t base = (((size_t)((b_ << 4) | h)) * 2048 + sbase) * 128;
#pragma unroll
        for (int r = 0; r < 4; ++r) {
          const float x1 = acc[i][2 * p][r], x2 = acc[i][2 * p + 1][r];
          k_out[base + ((size_t)r << 7) + d2]      = (bf16)(x1 * cc[r] - x2 * ss[r]);
          k_out[base + ((size_t)r << 7) + d2 + 64] = (bf16)(x1 * ss[r] + x2 * cc[r]);
        }
      } else {  // V transposed [B,H,128,S]
        bf16x4 v1, v2;
#pragma unroll
        for (int r = 0; r < 4; ++r) {
          v1[r] = (bf16)acc[i][2 * p][r];
          v2[r] = (bf16)acc[i][2 * p + 1][r];
        }
        const size_t hb = ((size_t)((b_ << 4) | h) << 18);
        *(bf16x4*)(v_out + hb + ((size_t)d2 << 11) + sbase) = v1;
        *(bf16x4*)(v_out + hb + ((size_t)(d2 + 64) << 11) + sbase) = v2;
      }
    }
  }
}

// ---------------- 128x128 BK=32 triple-buffer GEMM (out-proj), f32 out -------
template <int NTN>  // NTN = N/128 = 16
__global__ __launch_bounds__(256, 2) void gemm_o(const bf16* __restrict__ A,
                                                 const bf16* __restrict__ Bt,
                                                 float* __restrict__ f_out) {
  constexpr int K = 2048, NKT = 64;
  constexpr int BUFB = 16384;  // A 8192 + B 8192
  __shared__ char lds[3 * BUFB];  // 48 KiB
  const int nwg = 32 * NTN;  // 512
  const int id = blockIdx.x;
  const int swz = (id & 7) * (nwg >> 3) + (id >> 3);
  const int bx = swz % NTN, by = swz / NTN;
  const int m0 = by << 7, n0 = bx << 7;
  const int tid = threadIdx.x, w = tid >> 6, l = tid & 63;  // w in 0..3
  const int wm = w >> 1, wn = w & 1;
  const int lsl = (l & 7) ^ ((l >> 3) & 7);
  const int srow = ((l >> 3) << 1) + (lsl >> 2);
  const int scol = (lsl & 3) << 3;

  auto STAGE = [&](int t, char* base) {
    const int k0 = t << 5;
#pragma unroll
    for (int c = 0; c < 2; ++c) {
      const int row = (c << 6) + (w << 4) + srow;
      gll16(A + (size_t)(m0 + row) * K + k0 + scol, base + (c << 12) + (w << 10));
      gll16(Bt + (size_t)(n0 + row) * K + k0 + scol, base + 8192 + (c << 12) + (w << 10));
    }
  };

  f32x4 acc[4][4] = {};

  STAGE(0, (char*)lds);
  STAGE(1, (char*)lds + BUFB);
  asm volatile("s_waitcnt vmcnt(4)" ::: "memory");
  __builtin_amdgcn_s_barrier();

#pragma unroll 1
  for (int t = 0, bi = 0, bj = 2; t < NKT; ++t) {
    char* rbase = (char*)lds + bi * BUFB;
    bf16x8 af[4], bfr[4];
#pragma unroll
    for (int i = 0; i < 4; ++i) {
      const int row = (wm << 6) + (i << 4) + (l & 15);
      const int sr = row >> 1;
      af[i] = *(const bf16x8*)(rbase + sr * 128 +
                               (((((row & 1) << 2) | (l >> 4)) ^ (sr & 7)) << 4));
    }
#pragma unroll
    for (int j = 0; j < 4; ++j) {
      const int row = (wn << 6) + (j << 4) + (l & 15);
      const int sr = row >> 1;
      bfr[j] = *(const bf16x8*)(rbase + 8192 + sr * 128 +
                                (((((row & 1) << 2) | (l >> 4)) ^ (sr & 7)) << 4));
    }
    if (t + 2 < NKT) STAGE(t + 2, (char*)lds + bj * BUFB);
    asm volatile("s_waitcnt lgkmcnt(0)" ::: "memory");
    __builtin_amdgcn_sched_barrier(0);
    __builtin_amdgcn_s_setprio(1);
#pragma unroll
    for (int i = 0; i < 4; ++i)
#pragma unroll
      for (int j = 0; j < 4; ++j)
        acc[i][j] = mfma16(af[i], bfr[j], acc[i][j]);
    __builtin_amdgcn_s_setprio(0);
    if (t + 2 < NKT) {
      asm volatile("s_waitcnt vmcnt(4)" ::: "memory");
    } else if (t + 2 == NKT) {
      asm volatile("s_waitcnt vmcnt(0)" ::: "memory");
    }
    __builtin_amdgcn_sched_barrier(0);
    __builtin_amdgcn_s_barrier();
    bi = (bi == 2) ? 0 : bi + 1;
    bj = (bj == 2) ? 0 : bj + 1;
  }

#pragma unroll
  for (int i = 0; i < 4; ++i)
#pragma unroll
    for (int j = 0; j < 4; ++j)
#pragma unroll
      for (int r = 0; r < 4; ++r) {
        const int m = m0 + (wm << 6) + (i << 4) + ((l >> 4) << 2) + r;
        const int n = n0 + (wn << 6) + (j << 4) + (l & 15);
        f_out[(size_t)m * 2048 + n] = acc[i][j][r];
      }
}

// ---------------- causal flash attention, swapped-operand 32x32 ----------------
// grid 512; XCD-chunked swizzle + flip-pairing (CU pairs sum 17 tiles).
// Q-rope applied in-register at qf load (pairs qf[kt]/qf[kt+4]); QSCALE folded.
__global__ __launch_bounds__(256, 2) void attn_kernel(const bf16* __restrict__ Qb,
                                                      const bf16* __restrict__ Kb,
                                                      const bf16* __restrict__ Vt,
                                                      bf16* __restrict__ Ao,
                                                      const float* __restrict__ ctab,
                                                      const float* __restrict__ stab) {
  constexpr int S = 2048;
  __shared__ bf16 Ks[2][64 * 128];
  __shared__ bf16 Vs[2][128 * 64];
  const int id = blockIdx.x;
  const int swz = (id & 7) * 64 + (id >> 3);  // 512 blocks, 64 per XCD
  const int bh = swz >> 4;
  int qt = swz & 15;
  if ((swz >> 5) & 1) qt = 15 - qt;  // pair rounds within a CU: qt + (15-qt)
  const int q0 = qt << 7;
  const int tid = threadIdx.x, w = tid >> 6, l = tid & 63;
  const int hi = l >> 5;
  const bf16* Qp = Qb + ((size_t)bh << 18);
  const bf16* Kp = Kb + ((size_t)bh << 18);
  const bf16* Vp = Vt + ((size_t)bh << 18);

  auto STAGE_KV = [&](int kv0, int bufi) {
    char* Kbase = (char*)Ks + (bufi << 14);
    char* Vbase = (char*)Vs + (bufi << 14);
#pragma unroll
    for (int i = 0; i < 4; ++i) {
      const int rk = (w << 4) + (i << 2) + (l >> 4);
      gll16(Kp + ((size_t)(kv0 + rk) << 7) + (((l & 15) ^ (rk & 7)) << 3),
            Kbase + (w << 12) + (i << 10));
      const int rv = (w << 5) + (i << 3) + (l >> 3);
      gll16(Vp + (size_t)rv * S + kv0 + (((l & 7) ^ (rv & 7)) << 3),
            Vbase + (w << 12) + (i << 10));
    }
  };

  STAGE_KV(0, 0);  // start staging before Q-load/rope

  // Q fragments + in-register rope: qf[kt] holds d = kt*16+hi*8..+8 (d<64),
  // qf[kt+4] holds d+64 -> rotary pairs are lane-local.
  const int sq = q0 + (w << 5) + (l & 31);
  bf16x8 qf[8];
#pragma unroll
  for (int kt = 0; kt < 8; ++kt)
    qf[kt] = *(const bf16x8*)(Qp + ((size_t)sq << 7) + (kt << 4) + (hi << 3));
  {
    const float QS = 0.08838834764831845f * 1.4426950408889634f;  // 1/sqrt(dk)*log2e
#pragma unroll
    for (int kt = 0; kt < 4; ++kt) {
      const int d2 = (kt << 4) + (hi << 3);
      const float* cp = ctab + (sq << 6) + d2;
      const float* sp = stab + (sq << 6) + d2;
      float4 c0 = *(const float4*)cp, c1 = *(const float4*)(cp + 4);
      float4 s0 = *(const float4*)sp, s1 = *(const float4*)(sp + 4);
      const float cA[8] = {c0.x, c0.y, c0.z, c0.w, c1.x, c1.y, c1.z, c1.w};
      const float sA[8] = {s0.x, s0.y, s0.z, s0.w, s1.x, s1.y, s1.z, s1.w};
      const bf16x8 lo = qf[kt], up = qf[kt + 4];
#pragma unroll
      for (int j2 = 0; j2 < 8; ++j2) {
        const float a = (float)lo[j2], b2 = (float)up[j2];
        qf[kt][j2]     = (bf16)((a * cA[j2] - b2 * sA[j2]) * QS);
        qf[kt + 4][j2] = (bf16)((a * sA[j2] + b2 * cA[j2]) * QS);
      }
    }
  }

  f32x16 o[4] = {};
  float mrun = -3e38f, lrun = 0.f;

  const int qminw = q0 + (w << 5);
  const int qmaxw = qminw + 31;
  const int kv_end = q0 + 128;

  __syncthreads();

  int bufi = 0;
#pragma unroll 1
  for (int kv0 = 0; kv0 < kv_end; kv0 += 64, bufi ^= 1) {
    if (kv0 + 64 < kv_end) STAGE_KV(kv0 + 64, bufi ^ 1);
    if (kv0 <= qmaxw) {
      const char* Kbase = (const char*)Ks + (bufi << 14);
      const char* Vbase = (const char*)Vs + (bufi << 14);
      f32x16 sc0 = {}, sc1 = {};
      __builtin_amdgcn_s_setprio(1);
#pragma unroll
      for (int kt = 0; kt < 8; ++kt) {
        const int rk0 = l & 31;
        const int coff = ((kt << 5) + (hi << 4));
        bf16x8 k0 = *(const bf16x8*)(Kbase + (rk0 << 8) + (coff ^ ((rk0 & 7) << 4)));
        bf16x8 k1 = *(const bf16x8*)(Kbase + ((rk0 + 32) << 8) + (coff ^ ((rk0 & 7) << 4)));
        sc0 = mfma32(k0, qf[kt], sc0);
        sc1 = mfma32(k1, qf[kt], sc1);
      }
      __builtin_amdgcn_s_setprio(0);
      if (kv0 + 63 > qminw) {
        const int qg = qminw + (l & 31);
#pragma unroll
        for (int r = 0; r < 16; ++r) {
          const int kvr = kv0 + (r & 3) + ((r >> 2) << 3) + (hi << 2);
          if (kvr > qg) sc0[r] = -3e38f;
          if (kvr + 32 > qg) sc1[r] = -3e38f;
        }
      }
      float mx = -3e38f;
#pragma unroll
      for (int r = 0; r < 16; ++r) mx = fmaxf(mx, fmaxf(sc0[r], sc1[r]));
      mx = fmaxf(mx, __shfl_xor(mx, 32));
      const float mnew = fmaxf(mrun, mx);
      if (!__all(mx <= mrun)) {
        const float alpha = exp2f(mrun - mnew);
        lrun *= alpha;
#pragma unroll
        for (int dt = 0; dt < 4; ++dt) o[dt] *= alpha;
      }
      mrun = mnew;
      float ps = 0.f;
#pragma unroll
      for (int r = 0; r < 16; ++r) {
        sc0[r] = exp2f(sc0[r] - mnew); ps += sc0[r];
        sc1[r] = exp2f(sc1[r] - mnew); ps += sc1[r];
      }
      ps += __shfl_xor(ps, 32);
      lrun += ps;
#pragma unroll
      for (int ks = 0; ks < 4; ++ks) {
        const f32x16& s = (ks & 2) ? sc1 : sc0;
        const int rb = (ks & 1) << 3;
        int pa_ = cvtpk(s[rb + 0], s[rb + 1]);
        int pb_ = cvtpk(s[rb + 2], s[rb + 3]);
        int pc_ = cvtpk(s[rb + 4], s[rb + 5]);
        int pd_ = cvtpk(s[rb + 6], s[rb + 7]);
        int sa = __shfl_xor(pa_, 32), sb = __shfl_xor(pb_, 32);
        int sc_ = __shfl_xor(pc_, 32), sd = __shfl_xor(pd_, 32);
        i32x4 pi;
        pi[0] = hi ? sc_ : pa_;
        pi[1] = hi ? sd : pb_;
        pi[2] = hi ? pc_ : sa;
        pi[3] = hi ? pd_ : sb;
        const bf16x8 pf = __builtin_bit_cast(bf16x8, pi);
        __builtin_amdgcn_s_setprio(1);
#pragma unroll
        for (int dt = 0; dt < 4; ++dt) {
          const int rd = (dt << 5) + (l & 31);
          const bf16x8 vf = *(const bf16x8*)(Vbase + (rd << 7) +
                                             (((ks << 5) + (hi << 4)) ^ ((rd & 7) << 4)));
          o[dt] = mfma32(vf, pf, o[dt]);
        }
        __builtin_amdgcn_s_setprio(0);
      }
    }
    __syncthreads();
  }
  const float rinv = 1.0f / lrun;
  const int b = bh >> 4, h = bh & 15;
  bf16* Arow = Ao + (((size_t)(b * S + sq)) << 11) + (h << 7);
#pragma unroll
  for (int dt = 0; dt < 4; ++dt)
#pragma unroll
    for (int g = 0; g < 4; ++g) {
      bf16x4 ov;
#pragma unroll
      for (int r = 0; r < 4; ++r) ov[r] = (bf16)(o[dt][(g << 2) + r] * rinv);
      *(bf16x4*)(Arow + (dt << 5) + (g << 3) + (hi << 2)) = ov;
    }
}

// ---------------- launch ----------------
extern "C" void kernel_launch(void* const* d_in, const int* in_sizes, int n_in,
                              void* d_out, int out_size, void* d_ws, size_t ws_size,
                              hipStream_t stream) {
  const float* x = (const float*)d_in[0];      // [2,2048,2048]
  const float* w_qkv = (const float*)d_in[1];  // [6144,2048]
  const float* w_o = (const float*)d_in[2];    // [2048,2048]
  float* out = (float*)d_out;                  // [2,2048,2048] f32
  char* ws = (char*)d_ws;

  bf16* xb    = (bf16*)(ws);
  bf16* wqkvb = (bf16*)(ws + (16ull << 20));
  bf16* wob   = (bf16*)(ws + (40ull << 20));
  bf16* Qb    = (bf16*)(ws + (48ull << 20));
  bf16* Kb    = (bf16*)(ws + (64ull << 20));
  bf16* Vt    = (bf16*)(ws + (80ull << 20));
  bf16* Ao    = (bf16*)(ws + (96ull << 20));
  float* ctab = (float*)(ws + (112ull << 20));
  float* stab = (float*)(ws + (113ull << 20));

  prep_all<<<12800, 256, 0, stream>>>(x, w_qkv, w_o, xb, wqkvb, wob, ctab, stab);
  gemm384<<<256, 512, 0, stream>>>(xb, wqkvb, Qb, Kb, Vt, ctab, stab);
  attn_kernel<<<512, 256, 0, stream>>>(Qb, Kb, Vt, Ao, ctab, stab);
  gemm_o<16><<<512, 256, 0, stream>>>(Ao, wob, out);
}

// Round 13
// 244.130 us; speedup vs baseline: 1.3344x; 1.0032x over previous
//
#include <hip/hip_runtime.h>
#include <hip/hip_bf16.h>

// SimpleAttention fused block on MI355X (gfx950), bf16 MFMA pipeline.
// B=2, S=2048, D_MODEL=2048, H=16, DK=128.
//
// R13: attention restructured for uniform CU load:
//  - grid 256 = 32 bh x 8 pairs; block runs q-tile p THEN q-tile 15-p as one
//    flat 34-tile kv stream (uniform work, zero skip-tiles, staging dbuf
//    crosses the phase seam). 1 block/CU, all CUs busy start to finish.
//  - tree reductions: mx log-depth fold (depth 5), ps 4-accumulator (depth 10)
//    replacing 31/32-deep serial chains.
//  gemm384 / gemm_o / prep unchanged.
//
// ws layout (bytes):          size
//  xb      [4096,2048] bf16    16M @ 0
//  wqkvb   [6144,2048] bf16    24M @ 16M
//  wob     [2048,2048] bf16     8M @ 40M
//  Qb  [B,H,S,128] bf16        16M @ 48M   (raw, rope applied in attn)
//  Kb  [B,H,S,128] bf16        16M @ 64M   (roped by gemm384 epilogue)
//  Vt  [B,H,128,S] bf16        16M @ 80M
//  Ao  [B,S,2048]  bf16        16M @ 96M
//  ctab [2048,64] f32         512K @ 112M
//  stab [2048,64] f32         512K @ 113M

typedef __bf16 bf16;
typedef __bf16 bf16x4 __attribute__((ext_vector_type(4)));
typedef __bf16 bf16x8 __attribute__((ext_vector_type(8)));
typedef float f32x4 __attribute__((ext_vector_type(4)));
typedef float f32x16 __attribute__((ext_vector_type(16)));
typedef int i32x4 __attribute__((ext_vector_type(4)));

#define DEV __device__ __forceinline__

DEV void gll16(const void* g, void* lds_base_wave_uniform) {
  __builtin_amdgcn_global_load_lds((const __attribute__((address_space(1))) void*)g,
                                   (__attribute__((address_space(3))) void*)lds_base_wave_uniform,
                                   16, 0, 0);
}

DEV f32x4 mfma16(bf16x8 a, bf16x8 b, f32x4 c) {
  return __builtin_amdgcn_mfma_f32_16x16x32_bf16(a, b, c, 0, 0, 0);
}
DEV f32x16 mfma32(bf16x8 a, bf16x8 b, f32x16 c) {
  return __builtin_amdgcn_mfma_f32_32x32x16_bf16(a, b, c, 0, 0, 0);
}

DEV int cvtpk(float lo, float hi) {  // {hi:bf16(hi), lo:bf16(lo)}
  int r;
  asm("v_cvt_pk_bf16_f32 %0, %1, %2" : "=v"(r) : "v"(lo), "v"(hi));
  return r;
}

// ---------------- fused prep: 3x f32->bf16 cvt + rope tables ----------------
__global__ __launch_bounds__(256) void prep_all(const float* __restrict__ x,
                                                const float* __restrict__ wqkv,
                                                const float* __restrict__ wo,
                                                bf16* __restrict__ xb,
                                                bf16* __restrict__ wqkvb,
                                                bf16* __restrict__ wob,
                                                float* __restrict__ ctab,
                                                float* __restrict__ stab) {
  const int b = blockIdx.x;
  if (b < 12288) {
    const float* in;
    bf16* out;
    int bb = b;
    if (b < 4096) {
      in = x; out = xb;
    } else if (b < 10240) {
      in = wqkv; out = wqkvb; bb -= 4096;
    } else {
      in = wo; out = wob; bb -= 10240;
    }
    const int i = (bb * 256 + threadIdx.x) << 3;
    float4 a = *(const float4*)(in + i);
    float4 c = *(const float4*)(in + i + 4);
    bf16x8 o;
    o[0] = (bf16)a.x; o[1] = (bf16)a.y; o[2] = (bf16)a.z; o[3] = (bf16)a.w;
    o[4] = (bf16)c.x; o[5] = (bf16)c.y; o[6] = (bf16)c.z; o[7] = (bf16)c.w;
    *(bf16x8*)(out + i) = o;
  } else {
    // rope tables: freq[j] = 10000^(-j/63)  (linspace(0,1,64) inclusive!)
    const int id = (b - 12288) * 256 + threadIdx.x;  // 2048*64
    const int s = id >> 6, j = id & 63;
    float freq = powf(10000.0f, -(float)j / 63.0f);
    float th = (float)s * freq;
    ctab[id] = cosf(th);
    stab[id] = sinf(th);
  }
}

// ---------------- 256x384 BK=32 triple-buffer GEMM (QKV) + fused K-rope ------
__global__ __launch_bounds__(512, 2) void gemm384(const bf16* __restrict__ A,
                                                  const bf16* __restrict__ Bt,
                                                  bf16* __restrict__ q_out,
                                                  bf16* __restrict__ k_out,
                                                  bf16* __restrict__ v_out,
                                                  const float* __restrict__ ctab,
                                                  const float* __restrict__ stab) {
  constexpr int K = 2048, NKT = 64;
  constexpr int BUFB = 40960;  // A 16384 + B 24576
  __shared__ char lds[3 * BUFB];  // 120 KiB
  const int id = blockIdx.x;
  const int swz = (id & 7) * 32 + (id >> 3);  // XCD swizzle (256 blocks)
  const int bx = swz & 15, by = swz >> 4;
  const int m0 = by << 8;      // 256-row M tile
  const int n0 = bx * 384;     // 384-col N tile
  const int tid = threadIdx.x, w = tid >> 6, l = tid & 63;
  const int wm = w >> 2, wn = w & 3;
  const int lsl = (l & 7) ^ ((l >> 3) & 7);
  const int srow = ((l >> 3) << 1) + (lsl >> 2);
  const int scol = (lsl & 3) << 3;

  auto STAGE = [&](int t, char* base) {
    const int k0 = t << 5;
#pragma unroll
    for (int c = 0; c < 2; ++c) {  // A: 256 rows = 2 issues
      const int row = (c << 7) + (w << 4) + srow;
      gll16(A + (size_t)(m0 + row) * K + k0 + scol, base + (c << 13) + (w << 10));
    }
#pragma unroll
    for (int c = 0; c < 3; ++c) {  // B: 384 rows = 3 issues
      const int row = (c << 7) + (w << 4) + srow;
      gll16(Bt + (size_t)(n0 + row) * K + k0 + scol, base + 16384 + (c << 13) + (w << 10));
    }
  };

  f32x4 acc[8][6] = {};

  STAGE(0, (char*)lds);
  STAGE(1, (char*)lds + BUFB);
  asm volatile("s_waitcnt vmcnt(5)" ::: "memory");
  __builtin_amdgcn_s_barrier();

#pragma unroll 1
  for (int t = 0, bi = 0, bj = 2; t < NKT; ++t) {
    char* rbase = (char*)lds + bi * BUFB;
    bf16x8 bfr[6];
#pragma unroll
    for (int j = 0; j < 6; ++j) {
      // permuted: head-block j>>1, half (j&1)*64, cols wn*16..+15
      const int row = ((j >> 1) << 7) + ((j & 1) << 6) + (wn << 4) + (l & 15);
      const int sr = row >> 1;
      bfr[j] = *(const bf16x8*)(rbase + 16384 + sr * 128 +
                                (((((row & 1) << 2) | (l >> 4)) ^ (sr & 7)) << 4));
    }
    bf16x8 af[4];
#pragma unroll
    for (int i = 0; i < 4; ++i) {
      const int row = (wm << 7) + (i << 4) + (l & 15);
      const int sr = row >> 1;
      af[i] = *(const bf16x8*)(rbase + sr * 128 +
                               (((((row & 1) << 2) | (l >> 4)) ^ (sr & 7)) << 4));
    }
    if (t + 2 < NKT) STAGE(t + 2, (char*)lds + bj * BUFB);
    asm volatile("s_waitcnt lgkmcnt(0)" ::: "memory");
    __builtin_amdgcn_sched_barrier(0);
    __builtin_amdgcn_s_setprio(1);
#pragma unroll
    for (int i = 0; i < 4; ++i)
#pragma unroll
      for (int j = 0; j < 6; ++j)
        acc[i][j] = mfma16(af[i], bfr[j], acc[i][j]);
    __builtin_amdgcn_s_setprio(0);
#pragma unroll
    for (int i = 0; i < 4; ++i) {  // A frag-rows 4..7
      const int row = (wm << 7) + 64 + (i << 4) + (l & 15);
      const int sr = row >> 1;
      af[i] = *(const bf16x8*)(rbase + sr * 128 +
                               (((((row & 1) << 2) | (l >> 4)) ^ (sr & 7)) << 4));
    }
    asm volatile("s_waitcnt lgkmcnt(0)" ::: "memory");
    __builtin_amdgcn_sched_barrier(0);
    __builtin_amdgcn_s_setprio(1);
#pragma unroll
    for (int i = 0; i < 4; ++i)
#pragma unroll
      for (int j = 0; j < 6; ++j)
        acc[4 + i][j] = mfma16(af[i], bfr[j], acc[4 + i][j]);
    __builtin_amdgcn_s_setprio(0);
    if (t + 2 < NKT) {
      asm volatile("s_waitcnt vmcnt(5)" ::: "memory");
    } else if (t + 2 == NKT) {
      asm volatile("s_waitcnt vmcnt(0)" ::: "memory");
    }
    __builtin_amdgcn_sched_barrier(0);
    __builtin_amdgcn_s_barrier();
    bi = (bi == 2) ? 0 : bi + 1;
    bj = (bj == 2) ? 0 : bj + 1;
  }

  // epilogue: frag (i,j): m = m0+wm*128+i*16+(l>>4)*4+r;
  // col = n0 + (j>>1)*128 + (j&1)*64 + d2, d2 = wn*16+(l&15).
  const int d2 = (wn << 4) + (l & 15);
#pragma unroll
  for (int i = 0; i < 8; ++i) {
    const int mbase = m0 + (wm << 7) + (i << 4) + ((l >> 4) << 2);
    const int b_ = mbase >> 11, sbase = mbase & 2047;
    float cc[4], ss[4];
    if (((n0 + 256) >> 11) == 1 || (n0 >> 11) == 1) {  // any K head-block in tile
#pragma unroll
      for (int r = 0; r < 4; ++r) {
        cc[r] = ctab[((sbase + r) << 6) + d2];
        ss[r] = stab[((sbase + r) << 6) + d2];
      }
    }
#pragma unroll
    for (int p = 0; p < 3; ++p) {
      const int nb = n0 + (p << 7);
      const int which = nb >> 11;
      const int h = (nb >> 7) & 15;
      if (which == 0) {  // Q raw
        const size_t base = (((size_t)((b_ << 4) | h)) * 2048 + sbase) * 128;
#pragma unroll
        for (int r = 0; r < 4; ++r) {
          q_out[base + ((size_t)r << 7) + d2]      = (bf16)acc[i][2 * p][r];
          q_out[base + ((size_t)r << 7) + d2 + 64] = (bf16)acc[i][2 * p + 1][r];
        }
      } else if (which == 1) {  // K with fused rope (from f32 acc)
        const size_t base = (((size_t)((b_ << 4) | h)) * 2048 + sbase) * 128;
#pragma unroll
        for (int r = 0; r < 4; ++r) {
          const float x1 = acc[i][2 * p][r], x2 = acc[i][2 * p + 1][r];
          k_out[base + ((size_t)r << 7) + d2]      = (bf16)(x1 * cc[r] - x2 * ss[r]);
          k_out[base + ((size_t)r << 7) + d2 + 64] = (bf16)(x1 * ss[r] + x2 * cc[r]);
        }
      } else {  // V transposed [B,H,128,S]
        bf16x4 v1, v2;
#pragma unroll
        for (int r = 0; r < 4; ++r) {
          v1[r] = (bf16)acc[i][2 * p][r];
          v2[r] = (bf16)acc[i][2 * p + 1][r];
        }
        const size_t hb = ((size_t)((b_ << 4) | h) << 18);
        *(bf16x4*)(v_out + hb + ((size_t)d2 << 11) + sbase) = v1;
        *(bf16x4*)(v_out + hb + ((size_t)(d2 + 64) << 11) + sbase) = v2;
      }
    }
  }
}

// ---------------- 128x128 BK=32 triple-buffer GEMM (out-proj), f32 out -------
template <int NTN>  // NTN = N/128 = 16
__global__ __launch_bounds__(256, 2) void gemm_o(const bf16* __restrict__ A,
                                                 const bf16* __restrict__ Bt,
                                                 float* __restrict__ f_out) {
  constexpr int K = 2048, NKT = 64;
  constexpr int BUFB = 16384;  // A 8192 + B 8192
  __shared__ char lds[3 * BUFB];  // 48 KiB
  const int nwg = 32 * NTN;  // 512
  const int id = blockIdx.x;
  const int swz = (id & 7) * (nwg >> 3) + (id >> 3);
  const int bx = swz % NTN, by = swz / NTN;
  const int m0 = by << 7, n0 = bx << 7;
  const int tid = threadIdx.x, w = tid >> 6, l = tid & 63;  // w in 0..3
  const int wm = w >> 1, wn = w & 1;
  const int lsl = (l & 7) ^ ((l >> 3) & 7);
  const int srow = ((l >> 3) << 1) + (lsl >> 2);
  const int scol = (lsl & 3) << 3;

  auto STAGE = [&](int t, char* base) {
    const int k0 = t << 5;
#pragma unroll
    for (int c = 0; c < 2; ++c) {
      const int row = (c << 6) + (w << 4) + srow;
      gll16(A + (size_t)(m0 + row) * K + k0 + scol, base + (c << 12) + (w << 10));
      gll16(Bt + (size_t)(n0 + row) * K + k0 + scol, base + 8192 + (c << 12) + (w << 10));
    }
  };

  f32x4 acc[4][4] = {};

  STAGE(0, (char*)lds);
  STAGE(1, (char*)lds + BUFB);
  asm volatile("s_waitcnt vmcnt(4)" ::: "memory");
  __builtin_amdgcn_s_barrier();

#pragma unroll 1
  for (int t = 0, bi = 0, bj = 2; t < NKT; ++t) {
    char* rbase = (char*)lds + bi * BUFB;
    bf16x8 af[4], bfr[4];
#pragma unroll
    for (int i = 0; i < 4; ++i) {
      const int row = (wm << 6) + (i << 4) + (l & 15);
      const int sr = row >> 1;
      af[i] = *(const bf16x8*)(rbase + sr * 128 +
                               (((((row & 1) << 2) | (l >> 4)) ^ (sr & 7)) << 4));
    }
#pragma unroll
    for (int j = 0; j < 4; ++j) {
      const int row = (wn << 6) + (j << 4) + (l & 15);
      const int sr = row >> 1;
      bfr[j] = *(const bf16x8*)(rbase + 8192 + sr * 128 +
                                (((((row & 1) << 2) | (l >> 4)) ^ (sr & 7)) << 4));
    }
    if (t + 2 < NKT) STAGE(t + 2, (char*)lds + bj * BUFB);
    asm volatile("s_waitcnt lgkmcnt(0)" ::: "memory");
    __builtin_amdgcn_sched_barrier(0);
    __builtin_amdgcn_s_setprio(1);
#pragma unroll
    for (int i = 0; i < 4; ++i)
#pragma unroll
      for (int j = 0; j < 4; ++j)
        acc[i][j] = mfma16(af[i], bfr[j], acc[i][j]);
    __builtin_amdgcn_s_setprio(0);
    if (t + 2 < NKT) {
      asm volatile("s_waitcnt vmcnt(4)" ::: "memory");
    } else if (t + 2 == NKT) {
      asm volatile("s_waitcnt vmcnt(0)" ::: "memory");
    }
    __builtin_amdgcn_sched_barrier(0);
    __builtin_amdgcn_s_barrier();
    bi = (bi == 2) ? 0 : bi + 1;
    bj = (bj == 2) ? 0 : bj + 1;
  }

#pragma unroll
  for (int i = 0; i < 4; ++i)
#pragma unroll
    for (int j = 0; j < 4; ++j)
#pragma unroll
      for (int r = 0; r < 4; ++r) {
        const int m = m0 + (wm << 6) + (i << 4) + ((l >> 4) << 2) + r;
        const int n = n0 + (wn << 6) + (j << 4) + (l & 15);
        f_out[(size_t)m * 2048 + n] = acc[i][j][r];
      }
}

// ---------------- causal flash attention, swapped-operand 32x32 ----------------
// R13: grid 256 = 32 bh x 8 pairs. Block runs q-tile p then q-tile 15-p as one
// flat 34-tile kv stream (uniform work/CU, zero skip-tiles). XCD-chunked
// (4 bh per XCD). Q-rope in-register; tree reductions for mx / ps.
__global__ __launch_bounds__(256, 2) void attn_kernel(const bf16* __restrict__ Qb,
                                                      const bf16* __restrict__ Kb,
                                                      const bf16* __restrict__ Vt,
                                                      bf16* __restrict__ Ao,
                                                      const float* __restrict__ ctab,
                                                      const float* __restrict__ stab) {
  constexpr int S = 2048;
  __shared__ bf16 Ks[2][64 * 128];
  __shared__ bf16 Vs[2][128 * 64];
  const int id = blockIdx.x;
  const int swz = (id & 7) * 32 + (id >> 3);  // 256 blocks: 32 per XCD
  const int bh = swz >> 3;                    // 4 bh per XCD (4MB K/V -> L2)
  const int pp = swz & 7;
  const int ntA = (pp + 1) << 1;  // kv64 tiles for q-tile pp
  const int NT = 34;              // ntA + 2*(16-pp)
  const int tid = threadIdx.x, w = tid >> 6, l = tid & 63;
  const int hi = l >> 5;
  const bf16* Qp = Qb + ((size_t)bh << 18);
  const bf16* Kp = Kb + ((size_t)bh << 18);
  const bf16* Vp = Vt + ((size_t)bh << 18);

  auto STAGE_KV = [&](int kv0, int bufi) {
    char* Kbase = (char*)Ks + (bufi << 14);
    char* Vbase = (char*)Vs + (bufi << 14);
#pragma unroll
    for (int i = 0; i < 4; ++i) {
      const int rk = (w << 4) + (i << 2) + (l >> 4);
      gll16(Kp + ((size_t)(kv0 + rk) << 7) + (((l & 15) ^ (rk & 7)) << 3),
            Kbase + (w << 12) + (i << 10));
      const int rv = (w << 5) + (i << 3) + (l >> 3);
      gll16(Vp + (size_t)rv * S + kv0 + (((l & 7) ^ (rv & 7)) << 3),
            Vbase + (w << 12) + (i << 10));
    }
  };

  bf16x8 qf[8];
  auto LOAD_Q = [&](int q0_) {  // load + in-register rope + QSCALE
    const int sq = q0_ + (w << 5) + (l & 31);
#pragma unroll
    for (int kt = 0; kt < 8; ++kt)
      qf[kt] = *(const bf16x8*)(Qp + ((size_t)sq << 7) + (kt << 4) + (hi << 3));
    const float QS = 0.08838834764831845f * 1.4426950408889634f;
#pragma unroll
    for (int kt = 0; kt < 4; ++kt) {
      const int d2 = (kt << 4) + (hi << 3);
      const float* cp = ctab + (sq << 6) + d2;
      const float* sp = stab + (sq << 6) + d2;
      float4 c0 = *(const float4*)cp, c1 = *(const float4*)(cp + 4);
      float4 s0 = *(const float4*)sp, s1 = *(const float4*)(sp + 4);
      const float cA[8] = {c0.x, c0.y, c0.z, c0.w, c1.x, c1.y, c1.z, c1.w};
      const float sA[8] = {s0.x, s0.y, s0.z, s0.w, s1.x, s1.y, s1.z, s1.w};
      const bf16x8 lo = qf[kt], up = qf[kt + 4];
#pragma unroll
      for (int j2 = 0; j2 < 8; ++j2) {
        const float a = (float)lo[j2], b2 = (float)up[j2];
        qf[kt][j2]     = (bf16)((a * cA[j2] - b2 * sA[j2]) * QS);
        qf[kt + 4][j2] = (bf16)((a * sA[j2] + b2 * cA[j2]) * QS);
      }
    }
  };

  f32x16 o[4] = {};
  float mrun = -3e38f, lrun = 0.f;
  int q0 = pp << 7;

  auto EPILOGUE = [&](int q0_) {
    const float rinv = 1.0f / lrun;
    const int b = bh >> 4, h = bh & 15;
    const int sq = q0_ + (w << 5) + (l & 31);
    bf16* Arow = Ao + (((size_t)(b * S + sq)) << 11) + (h << 7);
#pragma unroll
    for (int dt = 0; dt < 4; ++dt)
#pragma unroll
      for (int g = 0; g < 4; ++g) {
        bf16x4 ov;
#pragma unroll
        for (int r = 0; r < 4; ++r) ov[r] = (bf16)(o[dt][(g << 2) + r] * rinv);
        *(bf16x4*)(Arow + (dt << 5) + (g << 3) + (hi << 2)) = ov;
      }
  };

  STAGE_KV(0, 0);
  LOAD_Q(q0);
  __syncthreads();

  int bufi = 0;
#pragma unroll 1
  for (int ti = 0; ti < NT; ++ti, bufi ^= 1) {
    const int kv0 = ((ti < ntA) ? ti : ti - ntA) << 6;
    if (ti + 1 < NT) {
      const int kv0n = ((ti + 1 < ntA) ? ti + 1 : ti + 1 - ntA) << 6;
      STAGE_KV(kv0n, bufi ^ 1);
    }
    const int qminw = q0 + (w << 5);
    if (kv0 <= qminw + 31) {
      const char* Kbase = (const char*)Ks + (bufi << 14);
      const char* Vbase = (const char*)Vs + (bufi << 14);
      f32x16 sc0 = {}, sc1 = {};
      __builtin_amdgcn_s_setprio(1);
#pragma unroll
      for (int kt = 0; kt < 8; ++kt) {
        const int rk0 = l & 31;
        const int coff = ((kt << 5) + (hi << 4));
        bf16x8 k0 = *(const bf16x8*)(Kbase + (rk0 << 8) + (coff ^ ((rk0 & 7) << 4)));
        bf16x8 k1 = *(const bf16x8*)(Kbase + ((rk0 + 32) << 8) + (coff ^ ((rk0 & 7) << 4)));
        sc0 = mfma32(k0, qf[kt], sc0);
        sc1 = mfma32(k1, qf[kt], sc1);
      }
      __builtin_amdgcn_s_setprio(0);
      if (kv0 + 63 > qminw) {  // diagonal masking
        const int qg = qminw + (l & 31);
#pragma unroll
        for (int r = 0; r < 16; ++r) {
          const int kvr = kv0 + (r & 3) + ((r >> 2) << 3) + (hi << 2);
          if (kvr > qg) sc0[r] = -3e38f;
          if (kvr + 32 > qg) sc1[r] = -3e38f;
        }
      }
      // ---- online softmax: tree reductions ----
      f32x16 mm;
#pragma unroll
      for (int r = 0; r < 16; ++r) mm[r] = fmaxf(sc0[r], sc1[r]);
#pragma unroll
      for (int off = 8; off; off >>= 1)
#pragma unroll
        for (int r = 0; r < off; ++r) mm[r] = fmaxf(mm[r], mm[r + off]);
      float mx = mm[0];
      mx = fmaxf(mx, __shfl_xor(mx, 32));
      const float mnew = fmaxf(mrun, mx);
      if (!__all(mx <= mrun)) {  // defer-rescale
        const float alpha = exp2f(mrun - mnew);
        lrun *= alpha;
#pragma unroll
        for (int dt = 0; dt < 4; ++dt) o[dt] *= alpha;
      }
      mrun = mnew;
      float p0 = 0.f, p1 = 0.f, p2 = 0.f, p3 = 0.f;
#pragma unroll
      for (int r = 0; r < 16; r += 2) {
        sc0[r] = exp2f(sc0[r] - mnew); sc0[r + 1] = exp2f(sc0[r + 1] - mnew);
        sc1[r] = exp2f(sc1[r] - mnew); sc1[r + 1] = exp2f(sc1[r + 1] - mnew);
        p0 += sc0[r]; p1 += sc0[r + 1]; p2 += sc1[r]; p3 += sc1[r + 1];
      }
      float ps = (p0 + p1) + (p2 + p3);
      ps += __shfl_xor(ps, 32);
      lrun += ps;
      // ---- PV ----
#pragma unroll
      for (int ks = 0; ks < 4; ++ks) {
        const f32x16& s = (ks & 2) ? sc1 : sc0;
        const int rb = (ks & 1) << 3;
        int pa_ = cvtpk(s[rb + 0], s[rb + 1]);
        int pb_ = cvtpk(s[rb + 2], s[rb + 3]);
        int pc_ = cvtpk(s[rb + 4], s[rb + 5]);
        int pd_ = cvtpk(s[rb + 6], s[rb + 7]);
        int sa = __shfl_xor(pa_, 32), sb = __shfl_xor(pb_, 32);
        int sc_ = __shfl_xor(pc_, 32), sd = __shfl_xor(pd_, 32);
        i32x4 pi;
        pi[0] = hi ? sc_ : pa_;
        pi[1] = hi ? sd : pb_;
        pi[2] = hi ? pc_ : sa;
        pi[3] = hi ? pd_ : sb;
        const bf16x8 pf = __builtin_bit_cast(bf16x8, pi);
        __builtin_amdgcn_s_setprio(1);
#pragma unroll
        for (int dt = 0; dt < 4; ++dt) {
          const int rd = (dt << 5) + (l & 31);
          const bf16x8 vf = *(const bf16x8*)(Vbase + (rd << 7) +
                                             (((ks << 5) + (hi << 4)) ^ ((rd & 7) << 4)));
          o[dt] = mfma32(vf, pf, o[dt]);
        }
        __builtin_amdgcn_s_setprio(0);
      }
    }
    if (ti == ntA - 1) {  // phase seam: write A, reset state, switch to B
      EPILOGUE(q0);
      q0 = (15 - pp) << 7;
#pragma unroll
      for (int dt = 0; dt < 4; ++dt)
#pragma unroll
        for (int r = 0; r < 16; ++r) o[dt][r] = 0.f;
      mrun = -3e38f; lrun = 0.f;
      LOAD_Q(q0);
    }
    __syncthreads();
  }
  EPILOGUE(q0);
}

// ---------------- launch ----------------
extern "C" void kernel_launch(void* const* d_in, const int* in_sizes, int n_in,
                              void* d_out, int out_size, void* d_ws, size_t ws_size,
                              hipStream_t stream) {
  const float* x = (const float*)d_in[0];      // [2,2048,2048]
  const float* w_qkv = (const float*)d_in[1];  // [6144,2048]
  const float* w_o = (const float*)d_in[2];    // [2048,2048]
  float* out = (float*)d_out;                  // [2,2048,2048] f32
  char* ws = (char*)d_ws;

  bf16* xb    = (bf16*)(ws);
  bf16* wqkvb = (bf16*)(ws + (16ull << 20));
  bf16* wob   = (bf16*)(ws + (40ull << 20));
  bf16* Qb    = (bf16*)(ws + (48ull << 20));
  bf16* Kb    = (bf16*)(ws + (64ull << 20));
  bf16* Vt    = (bf16*)(ws + (80ull << 20));
  bf16* Ao    = (bf16*)(ws + (96ull << 20));
  float* ctab = (float*)(ws + (112ull << 20));
  float* stab = (float*)(ws + (113ull << 20));

  prep_all<<<12800, 256, 0, stream>>>(x, w_qkv, w_o, xb, wqkvb, wob, ctab, stab);
  gemm384<<<256, 512, 0, stream>>>(xb, wqkvb, Qb, Kb, Vt, ctab, stab);
  attn_kernel<<<256, 256, 0, stream>>>(Qb, Kb, Vt, Ao, ctab, stab);
  gemm_o<16><<<512, 256, 0, stream>>>(Ao, wob, out);
}